// Round 3
// baseline (1263.448 us; speedup 1.0000x reference)
//
#include <hip/hip_runtime.h>
#include <hip/hip_fp16.h>
#include <stdint.h>

#define HH 100
#define WW 100
#define NPIX 10000
#define CIN 1024
#define COUT 1024
#define NA 9
#define NANCH 90000
#define PRE 6000
#define POST 300
#define MASKW 96
#define NW 94
#define K9 9216          // CIN*9
#define SPAD 10404       // 102*102 padded pixel rows
#define WSCALE 1024.0f   // exact pow2 pre-scale for w split (avoids fp16 subnormals)
#define KH 48            // padded head output count (9 cls + 36 box + 3 pad)
#define CANDN 8192       // selection capacity (top-6000 + threshold-bin ties)

// conv tiling
#define PXT 160          // px tile (grid 8 x 63 = 504 blocks, <=2/CU, XCD-even)
#define ABYTES 8192      // A plane: 128 rows x 64B
#define BBYTES 10240     // B plane: 160 rows x 64B
#define BUFB 36864       // A1+A2+B1+B2 per buffer
#define NSTEP 288        // 9 taps x 32 ci-steps

typedef unsigned short u16;
typedef _Float16 f16x8 __attribute__((ext_vector_type(8)));
typedef float f32x4 __attribute__((ext_vector_type(4)));

__device__ __forceinline__ void gload16(const u16* g, char* l)
{
    __builtin_amdgcn_global_load_lds((const void*)g, (void*)l, 16, 0, 0);
}

// ---------------------------------------------------------------------------
// xsplit: x fp32 [ci][px] -> xt1/xt2 fp16 [spx][ci] (padded-pixel major,
// ci contiguous). x = x1 + x2 + O(2^-22 x). Border rows zeroed by xborder.
// ---------------------------------------------------------------------------
__global__ __launch_bounds__(256) void xsplit(
    const float* __restrict__ x, u16* __restrict__ xt1, u16* __restrict__ xt2)
{
    __shared__ unsigned sh[32][257];   // [px_local][ci_local]: h1<<16 | h2
    const int t = threadIdx.x;
    const int px0 = blockIdx.x * 32;
    const int ci0 = blockIdx.y * 256;
    for (int it = 0; it < 32; ++it) {
        int idx = it * 256 + t;
        int a = idx >> 5, b = idx & 31;
        int p = px0 + b;
        float v = (p < NPIX) ? x[(size_t)(ci0 + a) * NPIX + p] : 0.f;
        __half h1 = __float2half_rn(v);
        __half h2 = __float2half_rn(v - __half2float(h1));
        sh[b][a] = ((unsigned)__half_as_ushort(h1) << 16) | __half_as_ushort(h2);
    }
    __syncthreads();
    for (int it = 0; it < 8; ++it) {
        int u = it * 256 + t;
        int pl = u >> 6, cq = u & 63;
        int p = px0 + pl;
        if (p >= NPIX) continue;
        int r = p / 100, c = p - r * 100;
        int spx = (r + 1) * 102 + (c + 1);
        unsigned w0 = sh[pl][cq * 4 + 0], w1 = sh[pl][cq * 4 + 1];
        unsigned w2 = sh[pl][cq * 4 + 2], w3 = sh[pl][cq * 4 + 3];
        ushort4 v1 = make_ushort4((u16)(w0 >> 16), (u16)(w1 >> 16), (u16)(w2 >> 16), (u16)(w3 >> 16));
        ushort4 v2 = make_ushort4((u16)(w0 & 0xffff), (u16)(w1 & 0xffff), (u16)(w2 & 0xffff), (u16)(w3 & 0xffff));
        size_t o = (size_t)spx * 1024 + ci0 + cq * 4;
        *(ushort4*)&xt1[o] = v1;
        *(ushort4*)&xt2[o] = v2;
    }
}

__global__ __launch_bounds__(256) void xborder(u16* __restrict__ xt1, u16* __restrict__ xt2)
{
    const int idx = blockIdx.x;            // 0..403
    int spx;
    if (idx < 102) spx = idx;
    else if (idx < 204) spx = 10302 + (idx - 102);
    else { int k = idx - 204; spx = (1 + (k >> 1)) * 102 + (k & 1) * 101; }
    const int t = threadIdx.x;
    size_t o = (size_t)spx * 1024 + t * 4;
    *(ushort4*)&xt1[o] = make_ushort4(0, 0, 0, 0);
    *(ushort4*)&xt2[o] = make_ushort4(0, 0, 0, 0);
}

// ---------------------------------------------------------------------------
// wsplit: w1 fp32 [co][ci*9+tap] -> wp1/wp2 fp16 [tap][co][ci], scaled x1024.
// ---------------------------------------------------------------------------
__global__ __launch_bounds__(256) void wsplit(
    const float* __restrict__ w1, u16* __restrict__ wp1, u16* __restrict__ wp2)
{
    __shared__ float sw[K9];
    const int t = threadIdx.x;
    const int co = blockIdx.x;
    for (int it = 0; it < 36; ++it)
        sw[it * 256 + t] = w1[(size_t)co * K9 + it * 256 + t];
    __syncthreads();
    for (int tap = 0; tap < 9; ++tap) {
        for (int it = 0; it < 4; ++it) {
            int ci = it * 256 + t;
            float v = sw[ci * 9 + tap] * WSCALE;
            __half h1 = __float2half_rn(v);
            __half h2 = __float2half_rn(v - __half2float(h1));
            size_t o = (size_t)tap * (COUT * 1024) + (size_t)co * 1024 + ci;
            wp1[o] = __half_as_ushort(h1);
            wp2[o] = __half_as_ushort(h2);
        }
    }
}

// ---------------------------------------------------------------------------
// conv_mfma: 3x3 conv via fp16-split MFMA. Block 128co x 160px, 256 thr,
// wave tile 64x80 (m4 x n5). K = 9 taps x 1024 ci, kstep 32.
// 2-phase pipeline: issue global_load_lds for step k+1 into buf^1, compute
// step k from buf, one barrier/step (drains vmcnt under the compute).
// LDS rows 64B linear (global_load_lds dest); bank spread via q-XOR swizzle
// applied on the per-lane GLOBAL source address + same XOR on ds_read.
// ---------------------------------------------------------------------------
__global__ __launch_bounds__(256, 2) void conv_mfma(
    const u16* __restrict__ xt1, const u16* __restrict__ xt2,
    const u16* __restrict__ wp1, const u16* __restrict__ wp2,
    const float* __restrict__ b1, float* __restrict__ y)
{
    __shared__ __align__(16) char lds[2 * BUFB];   // per buf: A1@0 A2@8192 B1@16384 B2@26624
    const int t = threadIdx.x;
    const int co0 = blockIdx.x * 128;
    const int px0 = blockIdx.y * PXT;
    const int lane = t & 63;
    const int wv = __builtin_amdgcn_readfirstlane(t >> 6);
    const int wm = (wv >> 1) * 64;          // co sub-tile
    const int wn = (wv & 1) * 80;           // px sub-tile

    // staging: lane i of a 16-row issue -> row r0+(i>>2), q=i&3; source column
    // chunk swizzled qs = q ^ ((i>>3)&3) (valid: all issue row-bases are
    // multiples of 8 with (r0>>1)&3 == 0)
    const int qs = (lane & 3) ^ ((lane >> 3) & 3);
    const int aln = (lane >> 2) * 1024 + qs * 8;   // elements within a plane chunk

    // A issues: wave wv stages co rows [wv*32, wv*32+32)
    const int ar0 = wv * 32, ar1 = wv * 32 + 16;
    const size_t aOff0 = (size_t)(co0 + ar0) * 1024 + aln;
    const size_t aOff1 = (size_t)(co0 + ar1) * 1024 + aln;

    // B issues: ids bj = wv + 4*s (s<3 for waves 0,1; s<2 for waves 2,3),
    // rows bj*16. Per-lane spx precomputed (rows are not affine in spx).
    const int nb = (wv < 2) ? 3 : 2;
    size_t bOff[3]; int bLds[3];
#pragma unroll
    for (int s = 0; s < 3; ++s) {
        int r0 = (wv + 4 * s) * 16;
        if (r0 >= PXT) r0 = 0;                    // unused slot
        int p = px0 + r0 + (lane >> 2);
        if (p > NPIX - 1) p = NPIX - 1;
        int rr = p / 100, cc = p - rr * 100;
        bOff[s] = (size_t)((rr + 1) * 102 + cc + 1) * 1024 + qs * 8;
        bLds[s] = r0 * 64;
    }

    // fragment reads: row = (wm|wn) + (lane&15) + {mi,ni}*16, chunk lane>>4;
    // read at swizzled chunk qf (same involution; row bases all have key 0)
    const int qf = ((lane >> 4) ^ (((lane & 15) >> 1) & 3)) * 16;
    const int fA = (wm + (lane & 15)) * 64 + qf;
    const int fB = 16384 + (wn + (lane & 15)) * 64 + qf;

    f32x4 acc[4][5] = {};

    auto STAGE = [&](int buf, int tap, int ci0) {
        const int dy = (tap * 11) >> 5;            // tap/3 for 0..8
        const int tsh = (dy - 1) * 102 + (tap - dy * 3) - 1;
        const size_t adelta = (size_t)tap * 1048576 + ci0;
        const ptrdiff_t bdelta = (ptrdiff_t)tsh * 1024 + ci0;
        char* lb = lds + buf * BUFB;
        gload16(wp1 + aOff0 + adelta, lb + ar0 * 64);
        gload16(wp1 + aOff1 + adelta, lb + ar1 * 64);
        gload16(wp2 + aOff0 + adelta, lb + ABYTES + ar0 * 64);
        gload16(wp2 + aOff1 + adelta, lb + ABYTES + ar1 * 64);
#pragma unroll
        for (int s = 0; s < 3; ++s) {
            if (s < nb) {
                gload16(xt1 + (ptrdiff_t)bOff[s] + bdelta, lb + 16384 + bLds[s]);
                gload16(xt2 + (ptrdiff_t)bOff[s] + bdelta, lb + 26624 + bLds[s]);
            }
        }
    };

    auto COMPUTE = [&](int buf) {
        const char* lb = lds + buf * BUFB;
        f16x8 A1[4], A2[4], B1[5], B2[5];
#pragma unroll
        for (int mi = 0; mi < 4; ++mi) {
            A1[mi] = *(const f16x8*)(lb + fA + mi * 1024);
            A2[mi] = *(const f16x8*)(lb + ABYTES + fA + mi * 1024);
        }
#pragma unroll
        for (int ni = 0; ni < 5; ++ni) {
            B1[ni] = *(const f16x8*)(lb + fB + ni * 1024);
            B2[ni] = *(const f16x8*)(lb + BBYTES + fB + ni * 1024);
        }
#pragma unroll
        for (int mi = 0; mi < 4; ++mi)
#pragma unroll
            for (int ni = 0; ni < 5; ++ni) {
                acc[mi][ni] = __builtin_amdgcn_mfma_f32_16x16x32_f16(A1[mi], B1[ni], acc[mi][ni], 0, 0, 0);
                acc[mi][ni] = __builtin_amdgcn_mfma_f32_16x16x32_f16(A1[mi], B2[ni], acc[mi][ni], 0, 0, 0);
                acc[mi][ni] = __builtin_amdgcn_mfma_f32_16x16x32_f16(A2[mi], B1[ni], acc[mi][ni], 0, 0, 0);
            }
    };

    STAGE(0, 0, 0);
    __syncthreads();                               // drains prologue vmcnt
    for (int kk = 0; kk < NSTEP - 1; ++kk) {
        const int kn = kk + 1;
        STAGE(kn & 1, kn >> 5, (kn & 31) << 5);    // issue next step's loads
        COMPUTE(kk & 1);                           // compute current
        __syncthreads();                           // drain in-flight loads + barrier
    }
    COMPUTE((NSTEP - 1) & 1);

    // epilogue: D row=(lane>>4)*4+reg (co), col=lane&15 (px); descale + bias + relu
    const int q4 = (lane >> 4) * 4, nl = lane & 15;
    const float inv = 1.0f / WSCALE;
#pragma unroll
    for (int mi = 0; mi < 4; ++mi) {
        const int cob = co0 + wm + mi * 16 + q4;
        const float bb0 = b1[cob + 0], bb1 = b1[cob + 1];
        const float bb2 = b1[cob + 2], bb3 = b1[cob + 3];
#pragma unroll
        for (int ni = 0; ni < 5; ++ni) {
            const int px = px0 + wn + ni * 16 + nl;
            if (px < NPIX) {
                y[(size_t)(cob + 0) * NPIX + px] = fmaxf(acc[mi][ni][0] * inv + bb0, 0.f);
                y[(size_t)(cob + 1) * NPIX + px] = fmaxf(acc[mi][ni][1] * inv + bb1, 0.f);
                y[(size_t)(cob + 2) * NPIX + px] = fmaxf(acc[mi][ni][2] * inv + bb2, 0.f);
                y[(size_t)(cob + 3) * NPIX + px] = fmaxf(acc[mi][ni][3] * inv + bb3, 0.f);
            }
        }
    }
}

// ---------------------------------------------------------------------------
// wh_prep: transpose head weights into wh[ci][48] so the 45 weights of one ci
// are contiguous (3 x s_load_dwordx16 per ci in rpn_head).
// ---------------------------------------------------------------------------
__global__ __launch_bounds__(256) void wh_prep(
    const float* __restrict__ wcls, const float* __restrict__ wbox,
    float* __restrict__ wh)
{
    int e = blockIdx.x * 256 + threadIdx.x;     // over CIN*KH
    if (e >= CIN * KH) return;
    int c = e / KH, k = e - c * KH;
    float v = 0.f;
    if (k < 9) v = wcls[k * CIN + c];
    else if (k < 45) v = wbox[(k - 9) * CIN + c];
    wh[e] = v;
}

// ---------------------------------------------------------------------------
// rpn_head (pixel-major): block = 64 px x 4 ci-quarters (256 thr).
// ---------------------------------------------------------------------------
__global__ __launch_bounds__(256) void rpn_head(
    const float* __restrict__ y, const float* __restrict__ wh,
    const float* __restrict__ bcls, const float* __restrict__ bbox,
    const float* __restrict__ am, const int* __restrict__ ishape,
    float* __restrict__ out_scores, float* __restrict__ out_deltas,
    float4* __restrict__ boxes, unsigned long long* __restrict__ keys)
{
    __shared__ float red[4][64][KH + 1];   // +1 pad: odd bank stride for reduce
    const int t = threadIdx.x;
    const int lane = t & 63;
    const int q = __builtin_amdgcn_readfirstlane(t >> 6);
    const int p = blockIdx.x * 64 + lane;
    const int pp = (p < NPIX) ? p : (NPIX - 1);

    float acc[45];
#pragma unroll
    for (int k = 0; k < 45; ++k) acc[k] = 0.f;

    const float* __restrict__ yq  = y  + (size_t)q * 256 * NPIX + pp;
    const float* __restrict__ whq = wh + (size_t)q * 256 * KH;
    for (int c = 0; c < 256; ++c) {
        float yv = yq[(size_t)c * NPIX];
        const float* wr = whq + c * KH;
#pragma unroll
        for (int k = 0; k < 45; ++k) acc[k] += yv * wr[k];
    }

#pragma unroll
    for (int k = 0; k < 45; ++k) red[q][lane][k] = acc[k];
    __syncthreads();

    if (t >= 64 || p >= NPIX) return;

    float s[45];
#pragma unroll
    for (int k = 0; k < 45; ++k)
        s[k] = (red[0][lane][k] + red[1][lane][k]) + (red[2][lane][k] + red[3][lane][k]);

    const float imh = (float)ishape[1], imw = (float)ishape[2];
#pragma unroll
    for (int a = 0; a < 9; ++a) {
        const int i = p * NA + a;
        float logit = s[a] + bcls[a];
        float score = 1.f / (1.f + expf(-logit));
        float d0 = s[9 + a * 4 + 0] + bbox[a * 4 + 0];
        float d1 = s[9 + a * 4 + 1] + bbox[a * 4 + 1];
        float d2 = s[9 + a * 4 + 2] + bbox[a * 4 + 2];
        float d3 = s[9 + a * 4 + 3] + bbox[a * 4 + 3];
        out_scores[i] = score;
        out_deltas[i * 4 + 0] = d0;
        out_deltas[i * 4 + 1] = d1;
        out_deltas[i * 4 + 2] = d2;
        out_deltas[i * 4 + 3] = d3;

        float cy = am[i * 4 + 0], cx = am[i * 4 + 1];
        float ah = am[i * 4 + 2], aw = am[i * 4 + 3];
        float ctry = cy + d0 * ah, ctrx = cx + d1 * aw;
        float hh = ah * expf(d2), ww = aw * expf(d3);
        float y1 = fmaxf(ctry - 0.5f * hh, 0.f);
        float x1 = fmaxf(ctrx - 0.5f * ww, 0.f);
        float y2 = fminf(ctry + 0.5f * hh, imh);
        float x2 = fminf(ctrx + 0.5f * ww, imw);
        boxes[i] = make_float4(y1, x1, y2, x2);
        unsigned sb = __float_as_uint(score);
        keys[i] = ((unsigned long long)sb << 32) | (unsigned)i;
    }
}

// ---------------------------------------------------------------------------
// Top-K selection replacing the full 131072-key bitonic sort (29 launches).
// Exactness: any key excluded by the prefix threshold has full u64 key smaller
// than every included key, so top-6000 set AND order are bit-identical.
// ---------------------------------------------------------------------------
__global__ __launch_bounds__(256) void score_hist(
    const unsigned long long* __restrict__ keys, unsigned* __restrict__ hist)
{
    int i = blockIdx.x * 256 + threadIdx.x;
    if (i < NANCH) atomicAdd(&hist[(unsigned)(keys[i] >> 48)], 1u);
}

// Find P = max prefix with count(key_prefix >= P) >= PRE. Single block.
__global__ __launch_bounds__(256) void score_thresh(
    const unsigned* __restrict__ hist, unsigned* __restrict__ Pout)
{
    __shared__ unsigned csum[256];
    __shared__ unsigned binv[256];
    __shared__ int bc[2];
    const int t = threadIdx.x;
    unsigned sum = 0;
    for (int i = 0; i < 256; ++i) sum += hist[t * 256 + i];
    csum[t] = sum;
    __syncthreads();
    if (t == 0) {
        unsigned cum = 0; int cstar = 0; unsigned cumPrev = 0;
        for (int c = 255; c >= 0; --c) {
            if (cum + csum[c] >= PRE) { cstar = c; cumPrev = cum; break; }
            cum += csum[c];
        }
        bc[0] = cstar; bc[1] = (int)cumPrev;
    }
    __syncthreads();
    const int cstar = bc[0];
    binv[t] = hist[cstar * 256 + t];
    __syncthreads();
    if (t == 0) {
        unsigned cum = (unsigned)bc[1];
        unsigned P = (unsigned)cstar * 256;
        for (int b = 255; b >= 0; --b) {
            cum += binv[b];
            if (cum >= PRE) { P = (unsigned)cstar * 256 + (unsigned)b; break; }
        }
        *Pout = P;
    }
}

__global__ __launch_bounds__(256) void score_compact(
    const unsigned long long* __restrict__ keys, const unsigned* __restrict__ Pout,
    unsigned long long* __restrict__ cand, unsigned* __restrict__ cnt)
{
    int i = blockIdx.x * 256 + threadIdx.x;
    if (i >= NANCH) return;
    unsigned long long k = keys[i];
    if ((unsigned)(k >> 48) >= *Pout) {
        unsigned pos = atomicAdd(cnt, 1u);
        if (pos < CANDN) cand[pos] = k;
    }
}

// Single-block bitonic sort (descending) of CANDN candidates in LDS, fused
// with the box gather + min-size valid ballot (replaces gather_sorted).
__global__ __launch_bounds__(1024) void sort_gather(
    const unsigned long long* __restrict__ cand, const unsigned* __restrict__ cnt,
    const float4* __restrict__ boxes,
    float4* __restrict__ box_s, unsigned long long* __restrict__ validw)
{
    __shared__ unsigned long long s[CANDN];
    const int t = threadIdx.x;
    int n = (int)*cnt; if (n > CANDN) n = CANDN;
    for (int k = t; k < CANDN; k += 1024)
        s[k] = (k < n) ? cand[k] : 0ull;
    for (int L = 2; L <= CANDN; L <<= 1) {
        for (int d = L >> 1; d >= 1; d >>= 1) {
            __syncthreads();
            for (int pr = t; pr < CANDN / 2; pr += 1024) {
                int i = ((pr & ~(d - 1)) << 1) | (pr & (d - 1));
                int j = i + d;
                bool desc = ((i & L) == 0);
                unsigned long long va = s[i], vb = s[j];
                bool sw = desc ? (va < vb) : (va > vb);
                if (sw) { s[i] = vb; s[j] = va; }
            }
        }
    }
    __syncthreads();
    for (int k = t; k < PRE; k += 1024) {
        unsigned idx = (unsigned)(s[k] & 0xffffffffull);
        float4 b = boxes[idx];
        box_s[k] = b;
        bool valid = ((b.z - b.x) >= 16.f) && ((b.w - b.y) >= 16.f);
        unsigned long long bal = __ballot(valid);
        if ((t & 63) == 0) validw[k >> 6] = bal;
    }
}

// ---------------------------------------------------------------------------
__global__ __launch_bounds__(128) void nms_mask(
    const float4* __restrict__ box_s, unsigned long long* __restrict__ mask)
{
    const int i = blockIdx.x;
    const int w = threadIdx.x;
    if (w >= NW) return;
    float4 bi = box_s[i];
    float areai = (bi.z - bi.x) * (bi.w - bi.y);
    unsigned long long m = 0ull;
    const int j0 = w * 64;
    if (j0 + 63 > i) {
#pragma unroll 4
        for (int b = 0; b < 64; ++b) {
            int j = j0 + b;
            if (j <= i || j >= PRE) continue;
            float4 bj = box_s[j];
            float areaj = (bj.z - bj.x) * (bj.w - bj.y);
            float iy1 = fmaxf(bi.x, bj.x), ix1 = fmaxf(bi.y, bj.y);
            float iy2 = fminf(bi.z, bj.z), ix2 = fminf(bi.w, bj.w);
            float inter = fmaxf(iy2 - iy1, 0.f) * fmaxf(ix2 - ix1, 0.f);
            float iou = inter / (areai + areaj - inter + 1e-8f);
            if (iou > 0.7f) m |= (1ull << b);
        }
    }
    mask[(size_t)i * MASKW + w] = m;
}

// ---------------------------------------------------------------------------
__global__ __launch_bounds__(64) void nms_scan(
    const unsigned long long* __restrict__ mask,
    const unsigned long long* __restrict__ validw,
    unsigned long long* __restrict__ keepw)
{
    const int l = threadIdx.x;
    unsigned long long r0 = ~validw[l];
    unsigned long long r1 = (l < NW - 64) ? ~validw[64 + l] : ~0ull;

    unsigned long long p0[16], p1[16];
#pragma unroll
    for (int k = 0; k < 16; ++k) {
        p0[k] = mask[(size_t)k * MASKW + l];
        p1[k] = (l < NW - 64) ? mask[(size_t)k * MASKW + 64 + l] : 0ull;
    }
    int kept = 0;
    for (int w = 0; w < NW && kept < POST; ++w) {
        unsigned long long Wc = (w < 64) ? __shfl(r0, w) : __shfl(r1, w - 64);
#pragma unroll 16
        for (int b = 0; b < 64; ++b) {
            int i = w * 64 + b;
            if (i >= PRE) break;
            int slot = i & 15;
            unsigned long long m0 = p0[slot], m1 = p1[slot];
            int nxt = i + 16;
            if (nxt < PRE) {
                p0[slot] = mask[(size_t)nxt * MASKW + l];
                p1[slot] = (l < NW - 64) ? mask[(size_t)nxt * MASKW + 64 + l] : 0ull;
            }
            if (!((Wc >> b) & 1ull)) {
                r0 |= m0; r1 |= m1;
                Wc = (w < 64) ? __shfl(r0, w) : __shfl(r1, w - 64);
                ++kept;
            }
        }
    }
    keepw[l] = ~r0;
    if (l < NW - 64) keepw[64 + l] = ~r1;
}

// ---------------------------------------------------------------------------
__global__ __launch_bounds__(256) void out_gather(
    const unsigned long long* __restrict__ keepw,
    const float4* __restrict__ box_s, float* __restrict__ outp)
{
    __shared__ unsigned long long kw_s[NW];
    __shared__ int prefix[NW];
    const int t = threadIdx.x;
    if (t < NW) kw_s[t] = keepw[t];
    __syncthreads();
    if (t == 0) {
        int cum = 0;
        for (int w = 0; w < NW; ++w) { prefix[w] = cum; cum += __popcll(kw_s[w]); }
    }
    for (int k = t; k < POST * 4; k += 256) outp[k] = 0.f;
    __syncthreads();
    for (int i = t; i < PRE; i += 256) {
        int w = i >> 6, b = i & 63;
        unsigned long long kw = kw_s[w];
        if ((kw >> b) & 1ull) {
            int rank = prefix[w] + __popcll(kw & ((1ull << b) - 1ull));
            if (rank < POST) {
                float4 bx = box_s[i];
                outp[rank * 4 + 0] = bx.x;
                outp[rank * 4 + 1] = bx.y;
                outp[rank * 4 + 2] = bx.z;
                outp[rank * 4 + 3] = bx.w;
            }
        }
    }
}

// ---------------------------------------------------------------------------
extern "C" void kernel_launch(void* const* d_in, const int* in_sizes, int n_in,
                              void* d_out, int out_size, void* d_ws, size_t ws_size,
                              hipStream_t stream)
{
    const float* x      = (const float*)d_in[0];
    const int*   ishape = (const int*)  d_in[1];
    const float* am     = (const float*)d_in[2];
    const float* w1   = (const float*)d_in[6];
    const float* b1   = (const float*)d_in[7];
    const float* wcls = (const float*)d_in[8];
    const float* bcls = (const float*)d_in[9];
    const float* wbox = (const float*)d_in[10];
    const float* bbox = (const float*)d_in[11];
    float* out = (float*)d_out;

    char* ws = (char*)d_ws;
    size_t off = 0;
    float* y  = (float*)(ws + off);  off += (size_t)COUT * NPIX * 4;
    u16* xt1  = (u16*)(ws + off);    off += (size_t)SPAD * 1024 * 2;
    u16* xt2  = (u16*)(ws + off);    off += (size_t)SPAD * 1024 * 2;
    u16* wp1  = (u16*)(ws + off);    off += (size_t)9 * COUT * 1024 * 2;
    u16* wp2  = (u16*)(ws + off);    off += (size_t)9 * COUT * 1024 * 2;
    float4* boxes = (float4*)(ws + off);              off += (size_t)NANCH * 16;
    unsigned long long* keys = (unsigned long long*)(ws + off); off += (size_t)NANCH * 8;
    float4* box_s = (float4*)(ws + off);              off += (size_t)PRE * 16;
    unsigned long long* validw = (unsigned long long*)(ws + off); off += 96 * 8;
    unsigned long long* keepw  = (unsigned long long*)(ws + off); off += 96 * 8;
    unsigned long long* maskb  = (unsigned long long*)(ws + off); off += (size_t)PRE * MASKW * 8;
    float* wh = (float*)(ws + off);  off += (size_t)CIN * KH * 4;
    unsigned* hist = (unsigned*)(ws + off); off += 65536 * 4;
    unsigned long long* cand = (unsigned long long*)(ws + off); off += (size_t)CANDN * 8;
    unsigned* cntP = (unsigned*)(ws + off); off += 64;   // [0]=count, [1]=P

    hipMemsetAsync(hist, 0, 65536 * 4, stream);
    hipMemsetAsync(cntP, 0, 64, stream);

    xsplit<<<dim3(313, 4), 256, 0, stream>>>(x, xt1, xt2);
    xborder<<<404, 256, 0, stream>>>(xt1, xt2);
    wsplit<<<COUT, 256, 0, stream>>>(w1, wp1, wp2);
    wh_prep<<<(CIN * KH + 255) / 256, 256, 0, stream>>>(wcls, wbox, wh);
    conv_mfma<<<dim3(8, (NPIX + PXT - 1) / PXT), 256, 0, stream>>>(xt1, xt2, wp1, wp2, b1, y);
    rpn_head<<<(NPIX + 63) / 64, 256, 0, stream>>>(y, wh, bcls, bbox, am, ishape,
                                                   out, out + NANCH, boxes, keys);
    score_hist<<<(NANCH + 255) / 256, 256, 0, stream>>>(keys, hist);
    score_thresh<<<1, 256, 0, stream>>>(hist, cntP + 1);
    score_compact<<<(NANCH + 255) / 256, 256, 0, stream>>>(keys, cntP + 1, cand, cntP);
    sort_gather<<<1, 1024, 0, stream>>>(cand, cntP, boxes, box_s, validw);
    nms_mask<<<PRE, 128, 0, stream>>>(box_s, maskb);
    nms_scan<<<1, 64, 0, stream>>>(maskb, validw, keepw);
    out_gather<<<1, 256, 0, stream>>>(keepw, box_s, out + (size_t)NANCH * 5);
}

// Round 4
// 1248.634 us; speedup vs baseline: 1.0119x; 1.0119x over previous
//
#include <hip/hip_runtime.h>
#include <hip/hip_fp16.h>
#include <stdint.h>

#define HH 100
#define WW 100
#define NPIX 10000
#define CIN 1024
#define COUT 1024
#define NA 9
#define NANCH 90000
#define PRE 6000
#define POST 300
#define MASKW 96
#define NW 94
#define K9 9216          // CIN*9
#define SPAD 10404       // 102*102 padded pixel rows
#define WSCALE 1024.0f   // exact pow2 pre-scale for w split (avoids fp16 subnormals)
#define KH 48            // padded head output count (9 cls + 36 box + 3 pad)
#define CANDN 8192       // selection capacity (top-6000 + threshold-bin ties)

// conv tiling
#define PXT 160          // px tile (grid 8 x 63 = 504 blocks, <=2/CU, XCD-even)
#define ABYTES 8192      // A plane: 128 rows x 64B
#define BBYTES 10240     // B plane: 160 rows x 64B
#define BUFB 36864       // A1+A2+B1+B2 per buffer
#define NSTEP 288        // 9 taps x 32 ci-steps

typedef unsigned short u16;
typedef _Float16 f16x8 __attribute__((ext_vector_type(8)));
typedef float f32x4 __attribute__((ext_vector_type(4)));

__device__ __forceinline__ void gload16(const u16* g, char* l)
{
    __builtin_amdgcn_global_load_lds((const void*)g, (void*)l, 16, 0, 0);
}

// ---------------------------------------------------------------------------
// xsplit: x fp32 [ci][px] -> xt1/xt2 fp16 [spx][ci] (padded-pixel major,
// ci contiguous). x = x1 + x2 + O(2^-22 x). Border rows zeroed by xborder.
// ---------------------------------------------------------------------------
__global__ __launch_bounds__(256) void xsplit(
    const float* __restrict__ x, u16* __restrict__ xt1, u16* __restrict__ xt2)
{
    __shared__ unsigned sh[32][257];   // [px_local][ci_local]: h1<<16 | h2
    const int t = threadIdx.x;
    const int px0 = blockIdx.x * 32;
    const int ci0 = blockIdx.y * 256;
    for (int it = 0; it < 32; ++it) {
        int idx = it * 256 + t;
        int a = idx >> 5, b = idx & 31;
        int p = px0 + b;
        float v = (p < NPIX) ? x[(size_t)(ci0 + a) * NPIX + p] : 0.f;
        __half h1 = __float2half_rn(v);
        __half h2 = __float2half_rn(v - __half2float(h1));
        sh[b][a] = ((unsigned)__half_as_ushort(h1) << 16) | __half_as_ushort(h2);
    }
    __syncthreads();
    for (int it = 0; it < 8; ++it) {
        int u = it * 256 + t;
        int pl = u >> 6, cq = u & 63;
        int p = px0 + pl;
        if (p >= NPIX) continue;
        int r = p / 100, c = p - r * 100;
        int spx = (r + 1) * 102 + (c + 1);
        unsigned w0 = sh[pl][cq * 4 + 0], w1 = sh[pl][cq * 4 + 1];
        unsigned w2 = sh[pl][cq * 4 + 2], w3 = sh[pl][cq * 4 + 3];
        ushort4 v1 = make_ushort4((u16)(w0 >> 16), (u16)(w1 >> 16), (u16)(w2 >> 16), (u16)(w3 >> 16));
        ushort4 v2 = make_ushort4((u16)(w0 & 0xffff), (u16)(w1 & 0xffff), (u16)(w2 & 0xffff), (u16)(w3 & 0xffff));
        size_t o = (size_t)spx * 1024 + ci0 + cq * 4;
        *(ushort4*)&xt1[o] = v1;
        *(ushort4*)&xt2[o] = v2;
    }
}

__global__ __launch_bounds__(256) void xborder(u16* __restrict__ xt1, u16* __restrict__ xt2)
{
    const int idx = blockIdx.x;            // 0..403
    int spx;
    if (idx < 102) spx = idx;
    else if (idx < 204) spx = 10302 + (idx - 102);
    else { int k = idx - 204; spx = (1 + (k >> 1)) * 102 + (k & 1) * 101; }
    const int t = threadIdx.x;
    size_t o = (size_t)spx * 1024 + t * 4;
    *(ushort4*)&xt1[o] = make_ushort4(0, 0, 0, 0);
    *(ushort4*)&xt2[o] = make_ushort4(0, 0, 0, 0);
}

// ---------------------------------------------------------------------------
// wsplit: w1 fp32 [co][ci*9+tap] -> wp1/wp2 fp16 [tap][co][ci], scaled x1024.
// ---------------------------------------------------------------------------
__global__ __launch_bounds__(256) void wsplit(
    const float* __restrict__ w1, u16* __restrict__ wp1, u16* __restrict__ wp2)
{
    __shared__ float sw[K9];
    const int t = threadIdx.x;
    const int co = blockIdx.x;
    for (int it = 0; it < 36; ++it)
        sw[it * 256 + t] = w1[(size_t)co * K9 + it * 256 + t];
    __syncthreads();
    for (int tap = 0; tap < 9; ++tap) {
        for (int it = 0; it < 4; ++it) {
            int ci = it * 256 + t;
            float v = sw[ci * 9 + tap] * WSCALE;
            __half h1 = __float2half_rn(v);
            __half h2 = __float2half_rn(v - __half2float(h1));
            size_t o = (size_t)tap * (COUT * 1024) + (size_t)co * 1024 + ci;
            wp1[o] = __half_as_ushort(h1);
            wp2[o] = __half_as_ushort(h2);
        }
    }
}

// ---------------------------------------------------------------------------
// conv_mfma: 3x3 conv via fp16-split MFMA. Block 128co x 160px, 256 thr,
// wave tile 64x80 (m4 x n5). K = 9 taps x 1024 ci, kstep 32.
// 2-phase pipeline: issue global_load_lds for step k+1 into buf^1, compute
// step k from buf, one barrier/step (drains vmcnt under the compute).
// LDS rows 64B linear (global_load_lds dest); bank spread via q-XOR swizzle
// applied on the per-lane GLOBAL source address + same XOR on ds_read.
// ---------------------------------------------------------------------------
__global__ __launch_bounds__(256, 2) void conv_mfma(
    const u16* __restrict__ xt1, const u16* __restrict__ xt2,
    const u16* __restrict__ wp1, const u16* __restrict__ wp2,
    const float* __restrict__ b1, float* __restrict__ y)
{
    __shared__ __align__(16) char lds[2 * BUFB];   // per buf: A1@0 A2@8192 B1@16384 B2@26624
    const int t = threadIdx.x;
    const int co0 = blockIdx.x * 128;
    const int px0 = blockIdx.y * PXT;
    const int lane = t & 63;
    const int wv = __builtin_amdgcn_readfirstlane(t >> 6);
    const int wm = (wv >> 1) * 64;          // co sub-tile
    const int wn = (wv & 1) * 80;           // px sub-tile

    // staging: lane i of a 16-row issue -> row r0+(i>>2), q=i&3; source column
    // chunk swizzled qs = q ^ ((i>>3)&3) (valid: all issue row-bases are
    // multiples of 8 with (r0>>1)&3 == 0)
    const int qs = (lane & 3) ^ ((lane >> 3) & 3);
    const int aln = (lane >> 2) * 1024 + qs * 8;   // elements within a plane chunk

    // A issues: wave wv stages co rows [wv*32, wv*32+32)
    const int ar0 = wv * 32, ar1 = wv * 32 + 16;
    const size_t aOff0 = (size_t)(co0 + ar0) * 1024 + aln;
    const size_t aOff1 = (size_t)(co0 + ar1) * 1024 + aln;

    // B issues: ids bj = wv + 4*s (s<3 for waves 0,1; s<2 for waves 2,3),
    // rows bj*16. Per-lane spx precomputed (rows are not affine in spx).
    const int nb = (wv < 2) ? 3 : 2;
    size_t bOff[3]; int bLds[3];
#pragma unroll
    for (int s = 0; s < 3; ++s) {
        int r0 = (wv + 4 * s) * 16;
        if (r0 >= PXT) r0 = 0;                    // unused slot
        int p = px0 + r0 + (lane >> 2);
        if (p > NPIX - 1) p = NPIX - 1;
        int rr = p / 100, cc = p - rr * 100;
        bOff[s] = (size_t)((rr + 1) * 102 + cc + 1) * 1024 + qs * 8;
        bLds[s] = r0 * 64;
    }

    // fragment reads: row = (wm|wn) + (lane&15) + {mi,ni}*16, chunk lane>>4;
    // read at swizzled chunk qf (same involution; row bases all have key 0)
    const int qf = ((lane >> 4) ^ (((lane & 15) >> 1) & 3)) * 16;
    const int fA = (wm + (lane & 15)) * 64 + qf;
    const int fB = 16384 + (wn + (lane & 15)) * 64 + qf;

    f32x4 acc[4][5] = {};

    auto STAGE = [&](int buf, int tap, int ci0) {
        const int dy = (tap * 11) >> 5;            // tap/3 for 0..8
        const int tsh = (dy - 1) * 102 + (tap - dy * 3) - 1;
        const size_t adelta = (size_t)tap * 1048576 + ci0;
        const ptrdiff_t bdelta = (ptrdiff_t)tsh * 1024 + ci0;
        char* lb = lds + buf * BUFB;
        gload16(wp1 + aOff0 + adelta, lb + ar0 * 64);
        gload16(wp1 + aOff1 + adelta, lb + ar1 * 64);
        gload16(wp2 + aOff0 + adelta, lb + ABYTES + ar0 * 64);
        gload16(wp2 + aOff1 + adelta, lb + ABYTES + ar1 * 64);
#pragma unroll
        for (int s = 0; s < 3; ++s) {
            if (s < nb) {
                gload16(xt1 + (ptrdiff_t)bOff[s] + bdelta, lb + 16384 + bLds[s]);
                gload16(xt2 + (ptrdiff_t)bOff[s] + bdelta, lb + 26624 + bLds[s]);
            }
        }
    };

    auto COMPUTE = [&](int buf) {
        const char* lb = lds + buf * BUFB;
        f16x8 A1[4], A2[4], B1[5], B2[5];
#pragma unroll
        for (int mi = 0; mi < 4; ++mi) {
            A1[mi] = *(const f16x8*)(lb + fA + mi * 1024);
            A2[mi] = *(const f16x8*)(lb + ABYTES + fA + mi * 1024);
        }
#pragma unroll
        for (int ni = 0; ni < 5; ++ni) {
            B1[ni] = *(const f16x8*)(lb + fB + ni * 1024);
            B2[ni] = *(const f16x8*)(lb + BBYTES + fB + ni * 1024);
        }
#pragma unroll
        for (int mi = 0; mi < 4; ++mi)
#pragma unroll
            for (int ni = 0; ni < 5; ++ni) {
                acc[mi][ni] = __builtin_amdgcn_mfma_f32_16x16x32_f16(A1[mi], B1[ni], acc[mi][ni], 0, 0, 0);
                acc[mi][ni] = __builtin_amdgcn_mfma_f32_16x16x32_f16(A1[mi], B2[ni], acc[mi][ni], 0, 0, 0);
                acc[mi][ni] = __builtin_amdgcn_mfma_f32_16x16x32_f16(A2[mi], B1[ni], acc[mi][ni], 0, 0, 0);
            }
    };

    STAGE(0, 0, 0);
    __syncthreads();                               // drains prologue vmcnt
    for (int kk = 0; kk < NSTEP - 1; ++kk) {
        const int kn = kk + 1;
        STAGE(kn & 1, kn >> 5, (kn & 31) << 5);    // issue next step's loads
        COMPUTE(kk & 1);                           // compute current
        __syncthreads();                           // drain in-flight loads + barrier
    }
    COMPUTE((NSTEP - 1) & 1);

    // epilogue: D row=(lane>>4)*4+reg (co), col=lane&15 (px); descale + bias + relu
    const int q4 = (lane >> 4) * 4, nl = lane & 15;
    const float inv = 1.0f / WSCALE;
#pragma unroll
    for (int mi = 0; mi < 4; ++mi) {
        const int cob = co0 + wm + mi * 16 + q4;
        const float bb0 = b1[cob + 0], bb1 = b1[cob + 1];
        const float bb2 = b1[cob + 2], bb3 = b1[cob + 3];
#pragma unroll
        for (int ni = 0; ni < 5; ++ni) {
            const int px = px0 + wn + ni * 16 + nl;
            if (px < NPIX) {
                y[(size_t)(cob + 0) * NPIX + px] = fmaxf(acc[mi][ni][0] * inv + bb0, 0.f);
                y[(size_t)(cob + 1) * NPIX + px] = fmaxf(acc[mi][ni][1] * inv + bb1, 0.f);
                y[(size_t)(cob + 2) * NPIX + px] = fmaxf(acc[mi][ni][2] * inv + bb2, 0.f);
                y[(size_t)(cob + 3) * NPIX + px] = fmaxf(acc[mi][ni][3] * inv + bb3, 0.f);
            }
        }
    }
}

// ---------------------------------------------------------------------------
// wh_prep: transpose head weights into wh[ci][48] so the 45 weights of one ci
// are contiguous (3 x s_load_dwordx16 per ci in rpn_head).
// ---------------------------------------------------------------------------
__global__ __launch_bounds__(256) void wh_prep(
    const float* __restrict__ wcls, const float* __restrict__ wbox,
    float* __restrict__ wh)
{
    int e = blockIdx.x * 256 + threadIdx.x;     // over CIN*KH
    if (e >= CIN * KH) return;
    int c = e / KH, k = e - c * KH;
    float v = 0.f;
    if (k < 9) v = wcls[k * CIN + c];
    else if (k < 45) v = wbox[(k - 9) * CIN + c];
    wh[e] = v;
}

// ---------------------------------------------------------------------------
// rpn_head (pixel-major): block = 64 px x 4 ci-quarters (256 thr).
// Fused: 16-bit-prefix histogram of the sort key (for exact top-K selection).
// ---------------------------------------------------------------------------
__global__ __launch_bounds__(256) void rpn_head(
    const float* __restrict__ y, const float* __restrict__ wh,
    const float* __restrict__ bcls, const float* __restrict__ bbox,
    const float* __restrict__ am, const int* __restrict__ ishape,
    float* __restrict__ out_scores, float* __restrict__ out_deltas,
    float4* __restrict__ boxes, unsigned long long* __restrict__ keys,
    unsigned* __restrict__ hist)
{
    __shared__ float red[4][64][KH + 1];   // +1 pad: odd bank stride for reduce
    const int t = threadIdx.x;
    const int lane = t & 63;
    const int q = __builtin_amdgcn_readfirstlane(t >> 6);
    const int p = blockIdx.x * 64 + lane;
    const int pp = (p < NPIX) ? p : (NPIX - 1);

    float acc[45];
#pragma unroll
    for (int k = 0; k < 45; ++k) acc[k] = 0.f;

    const float* __restrict__ yq  = y  + (size_t)q * 256 * NPIX + pp;
    const float* __restrict__ whq = wh + (size_t)q * 256 * KH;
    for (int c = 0; c < 256; ++c) {
        float yv = yq[(size_t)c * NPIX];
        const float* wr = whq + c * KH;
#pragma unroll
        for (int k = 0; k < 45; ++k) acc[k] += yv * wr[k];
    }

#pragma unroll
    for (int k = 0; k < 45; ++k) red[q][lane][k] = acc[k];
    __syncthreads();

    if (t >= 64 || p >= NPIX) return;

    float s[45];
#pragma unroll
    for (int k = 0; k < 45; ++k)
        s[k] = (red[0][lane][k] + red[1][lane][k]) + (red[2][lane][k] + red[3][lane][k]);

    const float imh = (float)ishape[1], imw = (float)ishape[2];
#pragma unroll
    for (int a = 0; a < 9; ++a) {
        const int i = p * NA + a;
        float logit = s[a] + bcls[a];
        float score = 1.f / (1.f + expf(-logit));
        float d0 = s[9 + a * 4 + 0] + bbox[a * 4 + 0];
        float d1 = s[9 + a * 4 + 1] + bbox[a * 4 + 1];
        float d2 = s[9 + a * 4 + 2] + bbox[a * 4 + 2];
        float d3 = s[9 + a * 4 + 3] + bbox[a * 4 + 3];
        out_scores[i] = score;
        out_deltas[i * 4 + 0] = d0;
        out_deltas[i * 4 + 1] = d1;
        out_deltas[i * 4 + 2] = d2;
        out_deltas[i * 4 + 3] = d3;

        float cy = am[i * 4 + 0], cx = am[i * 4 + 1];
        float ah = am[i * 4 + 2], aw = am[i * 4 + 3];
        float ctry = cy + d0 * ah, ctrx = cx + d1 * aw;
        float hh = ah * expf(d2), ww = aw * expf(d3);
        float y1 = fmaxf(ctry - 0.5f * hh, 0.f);
        float x1 = fmaxf(ctrx - 0.5f * ww, 0.f);
        float y2 = fminf(ctry + 0.5f * hh, imh);
        float x2 = fminf(ctrx + 0.5f * ww, imw);
        boxes[i] = make_float4(y1, x1, y2, x2);
        unsigned sb = __float_as_uint(score);
        keys[i] = ((unsigned long long)sb << 32) | (unsigned)i;
        atomicAdd(&hist[sb >> 16], 1u);
    }
}

// ---------------------------------------------------------------------------
// Exact top-K selection: threshold on the 16-bit key prefix, compact, then a
// MULTI-BLOCK bitonic over CANDN=8192 (r3's single-block version serialized
// 91 barriered passes on one CU — the regression).
// Exactness: excluded keys have prefix < P => full u64 key < every included
// key; zero-padding sorts last (real keys nonzero). Set AND order identical.
// ---------------------------------------------------------------------------
// Find P = max prefix with count(key_prefix >= P) >= PRE. Single tiny block.
__global__ __launch_bounds__(256) void score_thresh(
    const unsigned* __restrict__ hist, unsigned* __restrict__ Pout)
{
    __shared__ unsigned csum[256];
    __shared__ unsigned binv[256];
    __shared__ int bc[2];
    const int t = threadIdx.x;
    unsigned sum = 0;
    for (int i = 0; i < 256; ++i) sum += hist[t * 256 + i];
    csum[t] = sum;
    __syncthreads();
    if (t == 0) {
        unsigned cum = 0; int cstar = 0; unsigned cumPrev = 0;
        for (int c = 255; c >= 0; --c) {
            if (cum + csum[c] >= PRE) { cstar = c; cumPrev = cum; break; }
            cum += csum[c];
        }
        bc[0] = cstar; bc[1] = (int)cumPrev;
    }
    __syncthreads();
    const int cstar = bc[0];
    binv[t] = hist[cstar * 256 + t];
    __syncthreads();
    if (t == 0) {
        unsigned cum = (unsigned)bc[1];
        unsigned P = (unsigned)cstar * 256;
        for (int b = 255; b >= 0; --b) {
            cum += binv[b];
            if (cum >= PRE) { P = (unsigned)cstar * 256 + (unsigned)b; break; }
        }
        *Pout = P;
    }
}

__global__ __launch_bounds__(256) void score_compact(
    const unsigned long long* __restrict__ keys, const unsigned* __restrict__ Pout,
    unsigned long long* __restrict__ cand, unsigned* __restrict__ cnt)
{
    int i = blockIdx.x * 256 + threadIdx.x;
    if (i >= NANCH) return;
    unsigned long long k = keys[i];
    if ((unsigned)(k >> 48) >= *Pout) {
        unsigned pos = atomicAdd(cnt, 1u);
        if (pos < CANDN) cand[pos] = k;
    }
}

// ---------------------------------------------------------------------------
// Bitonic sort (descending) of CANDN u64 keys (multi-block).
// ---------------------------------------------------------------------------
__global__ __launch_bounds__(256) void bitonic_local(unsigned long long* keys)
{
    __shared__ unsigned long long s[2048];
    const int base = blockIdx.x * 2048, t = threadIdx.x;
    for (int k = t; k < 2048; k += 256) s[k] = keys[base + k];
    for (int L = 2; L <= 2048; L <<= 1) {
        for (int d = L >> 1; d >= 1; d >>= 1) {
            __syncthreads();
            for (int pr = t; pr < 1024; pr += 256) {
                int i = ((pr & ~(d - 1)) << 1) | (pr & (d - 1));
                int j = i + d;
                bool desc = (((base + i) & L) == 0);
                unsigned long long va = s[i], vb = s[j];
                bool sw = desc ? (va < vb) : (va > vb);
                if (sw) { s[i] = vb; s[j] = va; }
            }
        }
    }
    __syncthreads();
    for (int k = t; k < 2048; k += 256) keys[base + k] = s[k];
}

__global__ __launch_bounds__(256) void bitonic_gpass(unsigned long long* keys, int L, int d)
{
    int pr = blockIdx.x * 256 + threadIdx.x;
    int i = ((pr & ~(d - 1)) << 1) | (pr & (d - 1));
    int j = i + d;
    bool desc = ((i & L) == 0);
    unsigned long long va = keys[i], vb = keys[j];
    bool sw = desc ? (va < vb) : (va > vb);
    if (sw) { keys[i] = vb; keys[j] = va; }
}

__global__ __launch_bounds__(256) void bitonic_lmerge(unsigned long long* keys, int L)
{
    __shared__ unsigned long long s[2048];
    const int base = blockIdx.x * 2048, t = threadIdx.x;
    for (int k = t; k < 2048; k += 256) s[k] = keys[base + k];
    const bool desc = ((base & L) == 0);
    for (int d = 1024; d >= 1; d >>= 1) {
        __syncthreads();
        for (int pr = t; pr < 1024; pr += 256) {
            int i = ((pr & ~(d - 1)) << 1) | (pr & (d - 1));
            int j = i + d;
            unsigned long long va = s[i], vb = s[j];
            bool sw = desc ? (va < vb) : (va > vb);
            if (sw) { s[i] = vb; s[j] = va; }
        }
    }
    __syncthreads();
    for (int k = t; k < 2048; k += 256) keys[base + k] = s[k];
}

// ---------------------------------------------------------------------------
__global__ __launch_bounds__(256) void gather_sorted(
    const unsigned long long* __restrict__ keys, const float4* __restrict__ boxes,
    float4* __restrict__ box_s, unsigned long long* __restrict__ validw)
{
    int s = blockIdx.x * 256 + threadIdx.x;
    bool valid = false;
    if (s < PRE) {
        unsigned idx = (unsigned)(keys[s] & 0xffffffffull);
        float4 b = boxes[idx];
        box_s[s] = b;
        valid = ((b.z - b.x) >= 16.f) && ((b.w - b.y) >= 16.f);
    }
    unsigned long long bal = __ballot(valid);
    if ((threadIdx.x & 63) == 0) validw[s >> 6] = bal;
}

// ---------------------------------------------------------------------------
__global__ __launch_bounds__(128) void nms_mask(
    const float4* __restrict__ box_s, unsigned long long* __restrict__ mask)
{
    const int i = blockIdx.x;
    const int w = threadIdx.x;
    if (w >= NW) return;
    float4 bi = box_s[i];
    float areai = (bi.z - bi.x) * (bi.w - bi.y);
    unsigned long long m = 0ull;
    const int j0 = w * 64;
    if (j0 + 63 > i) {
#pragma unroll 4
        for (int b = 0; b < 64; ++b) {
            int j = j0 + b;
            if (j <= i || j >= PRE) continue;
            float4 bj = box_s[j];
            float areaj = (bj.z - bj.x) * (bj.w - bj.y);
            float iy1 = fmaxf(bi.x, bj.x), ix1 = fmaxf(bi.y, bj.y);
            float iy2 = fminf(bi.z, bj.z), ix2 = fminf(bi.w, bj.w);
            float inter = fmaxf(iy2 - iy1, 0.f) * fmaxf(ix2 - ix1, 0.f);
            float iou = inter / (areai + areaj - inter + 1e-8f);
            if (iou > 0.7f) m |= (1ull << b);
        }
    }
    mask[(size_t)i * MASKW + w] = m;
}

// ---------------------------------------------------------------------------
__global__ __launch_bounds__(64) void nms_scan(
    const unsigned long long* __restrict__ mask,
    const unsigned long long* __restrict__ validw,
    unsigned long long* __restrict__ keepw)
{
    const int l = threadIdx.x;
    unsigned long long r0 = ~validw[l];
    unsigned long long r1 = (l < NW - 64) ? ~validw[64 + l] : ~0ull;

    unsigned long long p0[16], p1[16];
#pragma unroll
    for (int k = 0; k < 16; ++k) {
        p0[k] = mask[(size_t)k * MASKW + l];
        p1[k] = (l < NW - 64) ? mask[(size_t)k * MASKW + 64 + l] : 0ull;
    }
    int kept = 0;
    for (int w = 0; w < NW && kept < POST; ++w) {
        unsigned long long Wc = (w < 64) ? __shfl(r0, w) : __shfl(r1, w - 64);
#pragma unroll 16
        for (int b = 0; b < 64; ++b) {
            int i = w * 64 + b;
            if (i >= PRE) break;
            int slot = i & 15;
            unsigned long long m0 = p0[slot], m1 = p1[slot];
            int nxt = i + 16;
            if (nxt < PRE) {
                p0[slot] = mask[(size_t)nxt * MASKW + l];
                p1[slot] = (l < NW - 64) ? mask[(size_t)nxt * MASKW + 64 + l] : 0ull;
            }
            if (!((Wc >> b) & 1ull)) {
                r0 |= m0; r1 |= m1;
                Wc = (w < 64) ? __shfl(r0, w) : __shfl(r1, w - 64);
                ++kept;
            }
        }
    }
    keepw[l] = ~r0;
    if (l < NW - 64) keepw[64 + l] = ~r1;
}

// ---------------------------------------------------------------------------
__global__ __launch_bounds__(256) void out_gather(
    const unsigned long long* __restrict__ keepw,
    const float4* __restrict__ box_s, float* __restrict__ outp)
{
    __shared__ unsigned long long kw_s[NW];
    __shared__ int prefix[NW];
    const int t = threadIdx.x;
    if (t < NW) kw_s[t] = keepw[t];
    __syncthreads();
    if (t == 0) {
        int cum = 0;
        for (int w = 0; w < NW; ++w) { prefix[w] = cum; cum += __popcll(kw_s[w]); }
    }
    for (int k = t; k < POST * 4; k += 256) outp[k] = 0.f;
    __syncthreads();
    for (int i = t; i < PRE; i += 256) {
        int w = i >> 6, b = i & 63;
        unsigned long long kw = kw_s[w];
        if ((kw >> b) & 1ull) {
            int rank = prefix[w] + __popcll(kw & ((1ull << b) - 1ull));
            if (rank < POST) {
                float4 bx = box_s[i];
                outp[rank * 4 + 0] = bx.x;
                outp[rank * 4 + 1] = bx.y;
                outp[rank * 4 + 2] = bx.z;
                outp[rank * 4 + 3] = bx.w;
            }
        }
    }
}

// ---------------------------------------------------------------------------
extern "C" void kernel_launch(void* const* d_in, const int* in_sizes, int n_in,
                              void* d_out, int out_size, void* d_ws, size_t ws_size,
                              hipStream_t stream)
{
    const float* x      = (const float*)d_in[0];
    const int*   ishape = (const int*)  d_in[1];
    const float* am     = (const float*)d_in[2];
    const float* w1   = (const float*)d_in[6];
    const float* b1   = (const float*)d_in[7];
    const float* wcls = (const float*)d_in[8];
    const float* bcls = (const float*)d_in[9];
    const float* wbox = (const float*)d_in[10];
    const float* bbox = (const float*)d_in[11];
    float* out = (float*)d_out;

    char* ws = (char*)d_ws;
    size_t off = 0;
    float* y  = (float*)(ws + off);  off += (size_t)COUT * NPIX * 4;
    u16* xt1  = (u16*)(ws + off);    off += (size_t)SPAD * 1024 * 2;
    u16* xt2  = (u16*)(ws + off);    off += (size_t)SPAD * 1024 * 2;
    u16* wp1  = (u16*)(ws + off);    off += (size_t)9 * COUT * 1024 * 2;
    u16* wp2  = (u16*)(ws + off);    off += (size_t)9 * COUT * 1024 * 2;
    float4* boxes = (float4*)(ws + off);              off += (size_t)NANCH * 16;
    unsigned long long* keys = (unsigned long long*)(ws + off); off += (size_t)NANCH * 8;
    float4* box_s = (float4*)(ws + off);              off += (size_t)PRE * 16;
    unsigned long long* validw = (unsigned long long*)(ws + off); off += 96 * 8;
    unsigned long long* keepw  = (unsigned long long*)(ws + off); off += 96 * 8;
    unsigned long long* maskb  = (unsigned long long*)(ws + off); off += (size_t)PRE * MASKW * 8;
    float* wh = (float*)(ws + off);  off += (size_t)CIN * KH * 4;
    unsigned* hist = (unsigned*)(ws + off); off += 65536 * 4;
    unsigned long long* cand = (unsigned long long*)(ws + off); off += (size_t)CANDN * 8;
    unsigned* cntP = (unsigned*)(ws + off); off += 64;   // [0]=count, [1]=P

    hipMemsetAsync(hist, 0, 65536 * 4, stream);
    hipMemsetAsync(cand, 0, (size_t)CANDN * 8, stream);
    hipMemsetAsync(cntP, 0, 64, stream);

    xsplit<<<dim3(313, 4), 256, 0, stream>>>(x, xt1, xt2);
    xborder<<<404, 256, 0, stream>>>(xt1, xt2);
    wsplit<<<COUT, 256, 0, stream>>>(w1, wp1, wp2);
    wh_prep<<<(CIN * KH + 255) / 256, 256, 0, stream>>>(wcls, wbox, wh);
    conv_mfma<<<dim3(8, (NPIX + PXT - 1) / PXT), 256, 0, stream>>>(xt1, xt2, wp1, wp2, b1, y);
    rpn_head<<<(NPIX + 63) / 64, 256, 0, stream>>>(y, wh, bcls, bbox, am, ishape,
                                                   out, out + NANCH, boxes, keys, hist);
    score_thresh<<<1, 256, 0, stream>>>(hist, cntP + 1);
    score_compact<<<(NANCH + 255) / 256, 256, 0, stream>>>(keys, cntP + 1, cand, cntP);
    bitonic_local<<<CANDN / 2048, 256, 0, stream>>>(cand);
    for (int L = 4096; L <= CANDN; L <<= 1) {
        for (int d = L >> 1; d >= 2048; d >>= 1)
            bitonic_gpass<<<CANDN / 512, 256, 0, stream>>>(cand, L, d);
        bitonic_lmerge<<<CANDN / 2048, 256, 0, stream>>>(cand, L);
    }
    gather_sorted<<<24, 256, 0, stream>>>(cand, boxes, box_s, validw);
    nms_mask<<<PRE, 128, 0, stream>>>(box_s, maskb);
    nms_scan<<<1, 64, 0, stream>>>(maskb, validw, keepw);
    out_gather<<<1, 256, 0, stream>>>(keepw, box_s, out + (size_t)NANCH * 5);
}

// Round 5
// 1177.827 us; speedup vs baseline: 1.0727x; 1.0601x over previous
//
#include <hip/hip_runtime.h>
#include <hip/hip_fp16.h>
#include <stdint.h>

#define HH 100
#define WW 100
#define NPIX 10000
#define CIN 1024
#define COUT 1024
#define NA 9
#define NANCH 90000
#define PRE 6000
#define POST 300
#define SORTN 131072
#define MASKW 96
#define NW 94
#define K9 9216          // CIN*9
#define SPAD 10404       // 102*102 padded pixel rows
#define WSCALE 1024.0f   // exact pow2 pre-scale for w split (avoids fp16 subnormals)
#define KH 48            // padded head output count (9 cls + 36 box + 3 pad)

// conv tiling
#define PXT 160          // px tile (grid 8 x 63 = 504 blocks, <=2/CU, XCD-even)
#define BBYTES 10240     // B plane: 160 rows x 64B
#define BUFB 20480       // B1+B2 per buffer (A is global->reg, no LDS)
#define NSTEP 288        // 9 taps x 32 ci-steps

typedef unsigned short u16;
typedef _Float16 f16x8 __attribute__((ext_vector_type(8)));
typedef float f32x4 __attribute__((ext_vector_type(4)));

__device__ __forceinline__ void gload16(const u16* g, char* l)
{
    __builtin_amdgcn_global_load_lds((const void*)g, (void*)l, 16, 0, 0);
}

// ---------------------------------------------------------------------------
// xsplit: x fp32 [ci][px] -> xt1/xt2 fp16 [spx][ci] (padded-pixel major,
// ci contiguous). x = x1 + x2 + O(2^-22 x). Border rows zeroed by xborder.
// ---------------------------------------------------------------------------
__global__ __launch_bounds__(256) void xsplit(
    const float* __restrict__ x, u16* __restrict__ xt1, u16* __restrict__ xt2)
{
    __shared__ unsigned sh[32][257];   // [px_local][ci_local]: h1<<16 | h2
    const int t = threadIdx.x;
    const int px0 = blockIdx.x * 32;
    const int ci0 = blockIdx.y * 256;
    for (int it = 0; it < 32; ++it) {
        int idx = it * 256 + t;
        int a = idx >> 5, b = idx & 31;
        int p = px0 + b;
        float v = (p < NPIX) ? x[(size_t)(ci0 + a) * NPIX + p] : 0.f;
        __half h1 = __float2half_rn(v);
        __half h2 = __float2half_rn(v - __half2float(h1));
        sh[b][a] = ((unsigned)__half_as_ushort(h1) << 16) | __half_as_ushort(h2);
    }
    __syncthreads();
    for (int it = 0; it < 8; ++it) {
        int u = it * 256 + t;
        int pl = u >> 6, cq = u & 63;
        int p = px0 + pl;
        if (p >= NPIX) continue;
        int r = p / 100, c = p - r * 100;
        int spx = (r + 1) * 102 + (c + 1);
        unsigned w0 = sh[pl][cq * 4 + 0], w1 = sh[pl][cq * 4 + 1];
        unsigned w2 = sh[pl][cq * 4 + 2], w3 = sh[pl][cq * 4 + 3];
        ushort4 v1 = make_ushort4((u16)(w0 >> 16), (u16)(w1 >> 16), (u16)(w2 >> 16), (u16)(w3 >> 16));
        ushort4 v2 = make_ushort4((u16)(w0 & 0xffff), (u16)(w1 & 0xffff), (u16)(w2 & 0xffff), (u16)(w3 & 0xffff));
        size_t o = (size_t)spx * 1024 + ci0 + cq * 4;
        *(ushort4*)&xt1[o] = v1;
        *(ushort4*)&xt2[o] = v2;
    }
}

__global__ __launch_bounds__(256) void xborder(u16* __restrict__ xt1, u16* __restrict__ xt2)
{
    const int idx = blockIdx.x;            // 0..403
    int spx;
    if (idx < 102) spx = idx;
    else if (idx < 204) spx = 10302 + (idx - 102);
    else { int k = idx - 204; spx = (1 + (k >> 1)) * 102 + (k & 1) * 101; }
    const int t = threadIdx.x;
    size_t o = (size_t)spx * 1024 + t * 4;
    *(ushort4*)&xt1[o] = make_ushort4(0, 0, 0, 0);
    *(ushort4*)&xt2[o] = make_ushort4(0, 0, 0, 0);
}

// ---------------------------------------------------------------------------
// wsplit: w1 fp32 [co][ci*9+tap] -> wpf1/wpf2 fp16 FRAGMENT-ORDERED, x1024:
//   element (co, ci, tap):  m=co>>4, r=co&15, g=ci>>5, chunk=(ci>>3)&3, j=ci&7
//   offset = ((tap*32+g)*64 + m)*512 + (r + chunk*16)*8 + j     (u16 units)
// A wave's 16x32 fragment (16 co rows x 32 ci) is then 1KB contiguous:
// lane (r + chunk*16) holds its 8 ci at offset lane*8 -> one coalesced
// global_load_dwordx4 per fragment, no LDS round-trip for weights.
// ---------------------------------------------------------------------------
__global__ __launch_bounds__(256) void wsplit(
    const float* __restrict__ w1, u16* __restrict__ wpf1, u16* __restrict__ wpf2)
{
    __shared__ float sw[K9];
    const int t = threadIdx.x;
    const int co = blockIdx.x;
    const int m = co >> 4, r = co & 15;
    for (int it = 0; it < 36; ++it)
        sw[it * 256 + t] = w1[(size_t)co * K9 + it * 256 + t];
    __syncthreads();
    for (int it = 0; it < 5; ++it) {
        int idx = it * 256 + t;               // over 9 taps x 128 ci-octets
        if (idx >= 1152) break;
        int tap = idx >> 7, oct = idx & 127;
        int g = oct >> 2, chunk = oct & 3;
        int ci0 = oct * 8;
        u16 h1v[8], h2v[8];
#pragma unroll
        for (int j = 0; j < 8; ++j) {
            float v = sw[(ci0 + j) * 9 + tap] * WSCALE;
            __half h1 = __float2half_rn(v);
            __half h2 = __float2half_rn(v - __half2float(h1));
            h1v[j] = __half_as_ushort(h1);
            h2v[j] = __half_as_ushort(h2);
        }
        size_t o = ((size_t)((tap * 32 + g) * 64) + m) * 512 + (size_t)(r + chunk * 16) * 8;
        *(ushort4*)&wpf1[o]     = make_ushort4(h1v[0], h1v[1], h1v[2], h1v[3]);
        *(ushort4*)&wpf1[o + 4] = make_ushort4(h1v[4], h1v[5], h1v[6], h1v[7]);
        *(ushort4*)&wpf2[o]     = make_ushort4(h2v[0], h2v[1], h2v[2], h2v[3]);
        *(ushort4*)&wpf2[o + 4] = make_ushort4(h2v[4], h2v[5], h2v[6], h2v[7]);
    }
}

// ---------------------------------------------------------------------------
// conv_mfma: 3x3 conv via fp16-split MFMA. Block 128co x 160px, 256 thr,
// wave tile 64x80 (m4 x n5). K = 9 taps x 1024 ci, kstep 32.
// A (weights): fragment-ordered global -> registers, double-buffered one step
// ahead (no LDS). B (activations): global_load_lds double-buffer, XOR bank
// swizzle via pre-swizzled global source + swizzled ds_read.
// LDS traffic/step/CU drops 218KB -> 122KB vs the A-in-LDS version.
// ---------------------------------------------------------------------------
__global__ __launch_bounds__(256, 2) void conv_mfma(
    const u16* __restrict__ xt1, const u16* __restrict__ xt2,
    const u16* __restrict__ wpf1, const u16* __restrict__ wpf2,
    const float* __restrict__ b1, float* __restrict__ y)
{
    __shared__ __align__(16) char lds[2 * BUFB];   // per buf: B1@0  B2@10240
    const int t = threadIdx.x;
    const int co0 = blockIdx.x * 128;
    const int px0 = blockIdx.y * PXT;
    const int lane = t & 63;
    const int wv = __builtin_amdgcn_readfirstlane(t >> 6);
    const int wm = (wv >> 1) * 64;          // co sub-tile
    const int wn = (wv & 1) * 80;           // px sub-tile
    const int cog = (co0 >> 4) + (wm >> 4); // A fragment m-base

    // B staging: lane i -> row r0+(i>>2), q=i&3; source chunk swizzled
    const int qs = (lane & 3) ^ ((lane >> 3) & 3);

    // B issues: ids bj = wv + 4*s (s<3 for waves 0,1; s<2 for waves 2,3)
    const int nb = (wv < 2) ? 3 : 2;
    size_t bOff[3]; int bLds[3];
#pragma unroll
    for (int s = 0; s < 3; ++s) {
        int r0 = (wv + 4 * s) * 16;
        if (r0 >= PXT) r0 = 0;                    // unused slot
        int p = px0 + r0 + (lane >> 2);
        if (p > NPIX - 1) p = NPIX - 1;
        int rr = p / 100, cc = p - rr * 100;
        bOff[s] = (size_t)((rr + 1) * 102 + cc + 1) * 1024 + qs * 8;
        bLds[s] = r0 * 64;
    }

    // B fragment reads: row = wn + (lane&15) + ni*16, chunk lane>>4, swizzled
    const int qf = ((lane >> 4) ^ (((lane & 15) >> 1) & 3)) * 16;
    const int fB = (wn + (lane & 15)) * 64 + qf;

    f32x4 acc[4][5] = {};
    f16x8 A1a[4], A2a[4], A1b[4], A2b[4];

    auto STAGE = [&](int buf, int step) {
        const int tap = step >> 5;
        const int ci0 = (step & 31) << 5;
        const int dy = (tap * 11) >> 5;            // tap/3 for 0..8
        const int tsh = (dy - 1) * 102 + (tap - dy * 3) - 1;
        const ptrdiff_t bdelta = (ptrdiff_t)tsh * 1024 + ci0;
        char* lb = lds + buf * BUFB;
#pragma unroll
        for (int s = 0; s < 3; ++s) {
            if (s < nb) {
                gload16(xt1 + (ptrdiff_t)bOff[s] + bdelta, lb + bLds[s]);
                gload16(xt2 + (ptrdiff_t)bOff[s] + bdelta, lb + BBYTES + bLds[s]);
            }
        }
    };

    auto LOADA = [&](f16x8* D1, f16x8* D2, int sp) {
        const size_t ab = ((size_t)sp * 64 + cog) * 512 + (size_t)(lane * 8);
#pragma unroll
        for (int mi = 0; mi < 4; ++mi) {
            D1[mi] = *(const f16x8*)(wpf1 + ab + mi * 512);
            D2[mi] = *(const f16x8*)(wpf2 + ab + mi * 512);
        }
    };

    auto COMPUTE = [&](int buf, const f16x8* A1, const f16x8* A2) {
        const char* lb = lds + buf * BUFB;
        f16x8 B1[5], B2[5];
#pragma unroll
        for (int ni = 0; ni < 5; ++ni) {
            B1[ni] = *(const f16x8*)(lb + fB + ni * 1024);
            B2[ni] = *(const f16x8*)(lb + BBYTES + fB + ni * 1024);
        }
#pragma unroll
        for (int mi = 0; mi < 4; ++mi)
#pragma unroll
            for (int ni = 0; ni < 5; ++ni) {
                acc[mi][ni] = __builtin_amdgcn_mfma_f32_16x16x32_f16(A1[mi], B1[ni], acc[mi][ni], 0, 0, 0);
                acc[mi][ni] = __builtin_amdgcn_mfma_f32_16x16x32_f16(A1[mi], B2[ni], acc[mi][ni], 0, 0, 0);
                acc[mi][ni] = __builtin_amdgcn_mfma_f32_16x16x32_f16(A2[mi], B1[ni], acc[mi][ni], 0, 0, 0);
            }
    };

    STAGE(0, 0);
    LOADA(A1a, A2a, 0);
    __syncthreads();                               // drains prologue loads
    for (int kk = 0; kk < NSTEP; kk += 2) {
        // even step kk: compute from buf0/Aa, prefetch kk+1 into buf1/Ab
        if (kk + 1 < NSTEP) STAGE(1, kk + 1);
        LOADA(A1b, A2b, (kk + 1 < NSTEP) ? kk + 1 : NSTEP - 1);
        COMPUTE(0, A1a, A2a);
        __syncthreads();
        // odd step kk+1: compute from buf1/Ab, prefetch kk+2 into buf0/Aa
        if (kk + 2 < NSTEP) STAGE(0, kk + 2);
        LOADA(A1a, A2a, (kk + 2 < NSTEP) ? kk + 2 : NSTEP - 1);
        COMPUTE(1, A1b, A2b);
        __syncthreads();
    }

    // epilogue: D row=(lane>>4)*4+reg (co), col=lane&15 (px); descale + bias + relu
    const int q4 = (lane >> 4) * 4, nl = lane & 15;
    const float inv = 1.0f / WSCALE;
#pragma unroll
    for (int mi = 0; mi < 4; ++mi) {
        const int cob = co0 + wm + mi * 16 + q4;
        const float bb0 = b1[cob + 0], bb1 = b1[cob + 1];
        const float bb2 = b1[cob + 2], bb3 = b1[cob + 3];
#pragma unroll
        for (int ni = 0; ni < 5; ++ni) {
            const int px = px0 + wn + ni * 16 + nl;
            if (px < NPIX) {
                y[(size_t)(cob + 0) * NPIX + px] = fmaxf(acc[mi][ni][0] * inv + bb0, 0.f);
                y[(size_t)(cob + 1) * NPIX + px] = fmaxf(acc[mi][ni][1] * inv + bb1, 0.f);
                y[(size_t)(cob + 2) * NPIX + px] = fmaxf(acc[mi][ni][2] * inv + bb2, 0.f);
                y[(size_t)(cob + 3) * NPIX + px] = fmaxf(acc[mi][ni][3] * inv + bb3, 0.f);
            }
        }
    }
}

// ---------------------------------------------------------------------------
// wh_prep: transpose head weights into wh[ci][48] so the 45 weights of one ci
// are contiguous.
// ---------------------------------------------------------------------------
__global__ __launch_bounds__(256) void wh_prep(
    const float* __restrict__ wcls, const float* __restrict__ wbox,
    float* __restrict__ wh)
{
    int e = blockIdx.x * 256 + threadIdx.x;     // over CIN*KH
    if (e >= CIN * KH) return;
    int c = e / KH, k = e - c * KH;
    float v = 0.f;
    if (k < 9) v = wcls[k * CIN + c];
    else if (k < 45) v = wbox[(k - 9) * CIN + c];
    wh[e] = v;
}

// ---------------------------------------------------------------------------
// rpn_head (pixel-major): block = 64 px x 4 ci-quarters (256 thr).
// ---------------------------------------------------------------------------
__global__ __launch_bounds__(256) void rpn_head(
    const float* __restrict__ y, const float* __restrict__ wh,
    const float* __restrict__ bcls, const float* __restrict__ bbox,
    const float* __restrict__ am, const int* __restrict__ ishape,
    float* __restrict__ out_scores, float* __restrict__ out_deltas,
    float4* __restrict__ boxes, unsigned long long* __restrict__ keys)
{
    __shared__ float red[4][64][KH + 1];   // +1 pad: odd bank stride for reduce
    const int t = threadIdx.x;
    const int lane = t & 63;
    const int q = __builtin_amdgcn_readfirstlane(t >> 6);
    const int p = blockIdx.x * 64 + lane;
    const int pp = (p < NPIX) ? p : (NPIX - 1);

    float acc[45];
#pragma unroll
    for (int k = 0; k < 45; ++k) acc[k] = 0.f;

    const float* __restrict__ yq  = y  + (size_t)q * 256 * NPIX + pp;
    const float* __restrict__ whq = wh + (size_t)q * 256 * KH;
    for (int c = 0; c < 256; ++c) {
        float yv = yq[(size_t)c * NPIX];
        const float* wr = whq + c * KH;
#pragma unroll
        for (int k = 0; k < 45; ++k) acc[k] += yv * wr[k];
    }

#pragma unroll
    for (int k = 0; k < 45; ++k) red[q][lane][k] = acc[k];
    __syncthreads();

    if (t >= 64 || p >= NPIX) return;

    float s[45];
#pragma unroll
    for (int k = 0; k < 45; ++k)
        s[k] = (red[0][lane][k] + red[1][lane][k]) + (red[2][lane][k] + red[3][lane][k]);

    const float imh = (float)ishape[1], imw = (float)ishape[2];
#pragma unroll
    for (int a = 0; a < 9; ++a) {
        const int i = p * NA + a;
        float logit = s[a] + bcls[a];
        float score = 1.f / (1.f + expf(-logit));
        float d0 = s[9 + a * 4 + 0] + bbox[a * 4 + 0];
        float d1 = s[9 + a * 4 + 1] + bbox[a * 4 + 1];
        float d2 = s[9 + a * 4 + 2] + bbox[a * 4 + 2];
        float d3 = s[9 + a * 4 + 3] + bbox[a * 4 + 3];
        out_scores[i] = score;
        out_deltas[i * 4 + 0] = d0;
        out_deltas[i * 4 + 1] = d1;
        out_deltas[i * 4 + 2] = d2;
        out_deltas[i * 4 + 3] = d3;

        float cy = am[i * 4 + 0], cx = am[i * 4 + 1];
        float ah = am[i * 4 + 2], aw = am[i * 4 + 3];
        float ctry = cy + d0 * ah, ctrx = cx + d1 * aw;
        float hh = ah * expf(d2), ww = aw * expf(d3);
        float y1 = fmaxf(ctry - 0.5f * hh, 0.f);
        float x1 = fmaxf(ctrx - 0.5f * ww, 0.f);
        float y2 = fminf(ctry + 0.5f * hh, imh);
        float x2 = fminf(ctrx + 0.5f * ww, imw);
        boxes[i] = make_float4(y1, x1, y2, x2);
        unsigned sb = __float_as_uint(score);
        keys[i] = ((unsigned long long)sb << 32) | (unsigned)i;
    }
}

// zero the sort-key padding region [NANCH, SORTN)
__global__ __launch_bounds__(256) void key_pad(unsigned long long* __restrict__ keys)
{
    int i = NANCH + blockIdx.x * 256 + threadIdx.x;
    if (i < SORTN) keys[i] = 0ull;
}

// ---------------------------------------------------------------------------
// Bitonic sort (descending) of SORTN u64 keys.
// ---------------------------------------------------------------------------
__global__ __launch_bounds__(256) void bitonic_local(unsigned long long* keys)
{
    __shared__ unsigned long long s[2048];
    const int base = blockIdx.x * 2048, t = threadIdx.x;
    for (int k = t; k < 2048; k += 256) s[k] = keys[base + k];
    for (int L = 2; L <= 2048; L <<= 1) {
        for (int d = L >> 1; d >= 1; d >>= 1) {
            __syncthreads();
            for (int pr = t; pr < 1024; pr += 256) {
                int i = ((pr & ~(d - 1)) << 1) | (pr & (d - 1));
                int j = i + d;
                bool desc = (((base + i) & L) == 0);
                unsigned long long va = s[i], vb = s[j];
                bool sw = desc ? (va < vb) : (va > vb);
                if (sw) { s[i] = vb; s[j] = va; }
            }
        }
    }
    __syncthreads();
    for (int k = t; k < 2048; k += 256) keys[base + k] = s[k];
}

__global__ __launch_bounds__(256) void bitonic_gpass(unsigned long long* keys, int L, int d)
{
    int pr = blockIdx.x * 256 + threadIdx.x;
    int i = ((pr & ~(d - 1)) << 1) | (pr & (d - 1));
    int j = i + d;
    bool desc = ((i & L) == 0);
    unsigned long long va = keys[i], vb = keys[j];
    bool sw = desc ? (va < vb) : (va > vb);
    if (sw) { keys[i] = vb; keys[j] = va; }
}

__global__ __launch_bounds__(256) void bitonic_lmerge(unsigned long long* keys, int L)
{
    __shared__ unsigned long long s[2048];
    const int base = blockIdx.x * 2048, t = threadIdx.x;
    for (int k = t; k < 2048; k += 256) s[k] = keys[base + k];
    const bool desc = ((base & L) == 0);
    for (int d = 1024; d >= 1; d >>= 1) {
        __syncthreads();
        for (int pr = t; pr < 1024; pr += 256) {
            int i = ((pr & ~(d - 1)) << 1) | (pr & (d - 1));
            int j = i + d;
            unsigned long long va = s[i], vb = s[j];
            bool sw = desc ? (va < vb) : (va > vb);
            if (sw) { s[i] = vb; s[j] = va; }
        }
    }
    __syncthreads();
    for (int k = t; k < 2048; k += 256) keys[base + k] = s[k];
}

// ---------------------------------------------------------------------------
__global__ __launch_bounds__(256) void gather_sorted(
    const unsigned long long* __restrict__ keys, const float4* __restrict__ boxes,
    float4* __restrict__ box_s, unsigned long long* __restrict__ validw)
{
    int s = blockIdx.x * 256 + threadIdx.x;
    bool valid = false;
    if (s < PRE) {
        unsigned idx = (unsigned)(keys[s] & 0xffffffffull);
        float4 b = boxes[idx];
        box_s[s] = b;
        valid = ((b.z - b.x) >= 16.f) && ((b.w - b.y) >= 16.f);
    }
    unsigned long long bal = __ballot(valid);
    if ((threadIdx.x & 63) == 0) validw[s >> 6] = bal;
}

// ---------------------------------------------------------------------------
__global__ __launch_bounds__(128) void nms_mask(
    const float4* __restrict__ box_s, unsigned long long* __restrict__ mask)
{
    const int i = blockIdx.x;
    const int w = threadIdx.x;
    if (w >= NW) return;
    float4 bi = box_s[i];
    float areai = (bi.z - bi.x) * (bi.w - bi.y);
    unsigned long long m = 0ull;
    const int j0 = w * 64;
    if (j0 + 63 > i) {
#pragma unroll 4
        for (int b = 0; b < 64; ++b) {
            int j = j0 + b;
            if (j <= i || j >= PRE) continue;
            float4 bj = box_s[j];
            float areaj = (bj.z - bj.x) * (bj.w - bj.y);
            float iy1 = fmaxf(bi.x, bj.x), ix1 = fmaxf(bi.y, bj.y);
            float iy2 = fminf(bi.z, bj.z), ix2 = fminf(bi.w, bj.w);
            float inter = fmaxf(iy2 - iy1, 0.f) * fmaxf(ix2 - ix1, 0.f);
            float iou = inter / (areai + areaj - inter + 1e-8f);
            if (iou > 0.7f) m |= (1ull << b);
        }
    }
    mask[(size_t)i * MASKW + w] = m;
}

// ---------------------------------------------------------------------------
__global__ __launch_bounds__(64) void nms_scan(
    const unsigned long long* __restrict__ mask,
    const unsigned long long* __restrict__ validw,
    unsigned long long* __restrict__ keepw)
{
    const int l = threadIdx.x;
    unsigned long long r0 = ~validw[l];
    unsigned long long r1 = (l < NW - 64) ? ~validw[64 + l] : ~0ull;

    unsigned long long p0[16], p1[16];
#pragma unroll
    for (int k = 0; k < 16; ++k) {
        p0[k] = mask[(size_t)k * MASKW + l];
        p1[k] = (l < NW - 64) ? mask[(size_t)k * MASKW + 64 + l] : 0ull;
    }
    int kept = 0;
    for (int w = 0; w < NW && kept < POST; ++w) {
        unsigned long long Wc = (w < 64) ? __shfl(r0, w) : __shfl(r1, w - 64);
#pragma unroll 16
        for (int b = 0; b < 64; ++b) {
            int i = w * 64 + b;
            if (i >= PRE) break;
            int slot = i & 15;
            unsigned long long m0 = p0[slot], m1 = p1[slot];
            int nxt = i + 16;
            if (nxt < PRE) {
                p0[slot] = mask[(size_t)nxt * MASKW + l];
                p1[slot] = (l < NW - 64) ? mask[(size_t)nxt * MASKW + 64 + l] : 0ull;
            }
            if (!((Wc >> b) & 1ull)) {
                r0 |= m0; r1 |= m1;
                Wc = (w < 64) ? __shfl(r0, w) : __shfl(r1, w - 64);
                ++kept;
            }
        }
    }
    keepw[l] = ~r0;
    if (l < NW - 64) keepw[64 + l] = ~r1;
}

// ---------------------------------------------------------------------------
__global__ __launch_bounds__(256) void out_gather(
    const unsigned long long* __restrict__ keepw,
    const float4* __restrict__ box_s, float* __restrict__ outp)
{
    __shared__ unsigned long long kw_s[NW];
    __shared__ int prefix[NW];
    const int t = threadIdx.x;
    if (t < NW) kw_s[t] = keepw[t];
    __syncthreads();
    if (t == 0) {
        int cum = 0;
        for (int w = 0; w < NW; ++w) { prefix[w] = cum; cum += __popcll(kw_s[w]); }
    }
    for (int k = t; k < POST * 4; k += 256) outp[k] = 0.f;
    __syncthreads();
    for (int i = t; i < PRE; i += 256) {
        int w = i >> 6, b = i & 63;
        unsigned long long kw = kw_s[w];
        if ((kw >> b) & 1ull) {
            int rank = prefix[w] + __popcll(kw & ((1ull << b) - 1ull));
            if (rank < POST) {
                float4 bx = box_s[i];
                outp[rank * 4 + 0] = bx.x;
                outp[rank * 4 + 1] = bx.y;
                outp[rank * 4 + 2] = bx.z;
                outp[rank * 4 + 3] = bx.w;
            }
        }
    }
}

// ---------------------------------------------------------------------------
extern "C" void kernel_launch(void* const* d_in, const int* in_sizes, int n_in,
                              void* d_out, int out_size, void* d_ws, size_t ws_size,
                              hipStream_t stream)
{
    const float* x      = (const float*)d_in[0];
    const int*   ishape = (const int*)  d_in[1];
    const float* am     = (const float*)d_in[2];
    const float* w1   = (const float*)d_in[6];
    const float* b1   = (const float*)d_in[7];
    const float* wcls = (const float*)d_in[8];
    const float* bcls = (const float*)d_in[9];
    const float* wbox = (const float*)d_in[10];
    const float* bbox = (const float*)d_in[11];
    float* out = (float*)d_out;

    char* ws = (char*)d_ws;
    size_t off = 0;
    float* y  = (float*)(ws + off);  off += (size_t)COUT * NPIX * 4;
    u16* xt1  = (u16*)(ws + off);    off += (size_t)SPAD * 1024 * 2;
    u16* xt2  = (u16*)(ws + off);    off += (size_t)SPAD * 1024 * 2;
    u16* wpf1 = (u16*)(ws + off);    off += (size_t)9 * COUT * 1024 * 2;
    u16* wpf2 = (u16*)(ws + off);    off += (size_t)9 * COUT * 1024 * 2;
    float4* boxes = (float4*)(ws + off);              off += (size_t)NANCH * 16;
    unsigned long long* keys = (unsigned long long*)(ws + off); off += (size_t)SORTN * 8;
    float4* box_s = (float4*)(ws + off);              off += (size_t)PRE * 16;
    unsigned long long* validw = (unsigned long long*)(ws + off); off += 96 * 8;
    unsigned long long* keepw  = (unsigned long long*)(ws + off); off += 96 * 8;
    unsigned long long* maskb  = (unsigned long long*)(ws + off); off += (size_t)PRE * MASKW * 8;
    float* wh = (float*)(ws + off);  off += (size_t)CIN * KH * 4;

    xsplit<<<dim3(313, 4), 256, 0, stream>>>(x, xt1, xt2);
    xborder<<<404, 256, 0, stream>>>(xt1, xt2);
    wsplit<<<COUT, 256, 0, stream>>>(w1, wpf1, wpf2);
    wh_prep<<<(CIN * KH + 255) / 256, 256, 0, stream>>>(wcls, wbox, wh);
    conv_mfma<<<dim3(8, (NPIX + PXT - 1) / PXT), 256, 0, stream>>>(xt1, xt2, wpf1, wpf2, b1, y);
    rpn_head<<<(NPIX + 63) / 64, 256, 0, stream>>>(y, wh, bcls, bbox, am, ishape,
                                                   out, out + NANCH, boxes, keys);
    key_pad<<<(SORTN - NANCH + 255) / 256, 256, 0, stream>>>(keys);
    bitonic_local<<<SORTN / 2048, 256, 0, stream>>>(keys);
    for (int L = 4096; L <= SORTN; L <<= 1) {
        for (int d = L >> 1; d >= 2048; d >>= 1)
            bitonic_gpass<<<SORTN / 512, 256, 0, stream>>>(keys, L, d);
        bitonic_lmerge<<<SORTN / 2048, 256, 0, stream>>>(keys, L);
    }
    gather_sorted<<<24, 256, 0, stream>>>(keys, boxes, box_s, validw);
    nms_mask<<<PRE, 128, 0, stream>>>(box_s, maskb);
    nms_scan<<<1, 64, 0, stream>>>(maskb, validw, keepw);
    out_gather<<<1, 256, 0, stream>>>(keepw, box_s, out + (size_t)NANCH * 5);
}

// Round 6
// 1147.818 us; speedup vs baseline: 1.1007x; 1.0261x over previous
//
#include <hip/hip_runtime.h>
#include <hip/hip_fp16.h>
#include <stdint.h>

#define HH 100
#define WW 100
#define NPIX 10000
#define CIN 1024
#define COUT 1024
#define NA 9
#define NANCH 90000
#define PRE 6000
#define POST 300
#define SORTN 131072
#define MASKW 96
#define NW 94
#define K9 9216          // CIN*9
#define SPAD 10404       // 102*102 padded pixel rows
#define WSCALE 1024.0f   // exact pow2 pre-scale for w split (avoids fp16 subnormals)
#define KH 48            // padded head output count (9 cls + 36 box + 3 pad)

// conv tiling (R2 structure: best measured, 528us)
#define PXT 160          // px tile (grid 8 x 63 = 504 blocks, <=2/CU, XCD-even)
#define ABYTES 8192      // A plane: 128 rows x 64B
#define BBYTES 10240     // B plane: 160 rows x 64B
#define BUFB 36864       // A1+A2+B1+B2 per buffer
#define NSTEP 288        // 9 taps x 32 ci-steps

#define HEADB 157        // rpn_head real blocks = (NPIX+63)/64

typedef unsigned short u16;
typedef _Float16 f16x8 __attribute__((ext_vector_type(8)));
typedef float f32x4 __attribute__((ext_vector_type(4)));

__device__ __forceinline__ void gload16(const u16* g, char* l)
{
    __builtin_amdgcn_global_load_lds((const void*)g, (void*)l, 16, 0, 0);
}

// ---------------------------------------------------------------------------
// xsplit (+fused border zeroing): x fp32 [ci][px] -> xt1/xt2 fp16 [spx][ci].
// Blocks x>=313 zero the 404 border rows instead (idx = (bx-313)*4 + by).
// ---------------------------------------------------------------------------
__global__ __launch_bounds__(256) void xsplit(
    const float* __restrict__ x, u16* __restrict__ xt1, u16* __restrict__ xt2)
{
    __shared__ unsigned sh[32][257];   // [px_local][ci_local]: h1<<16 | h2
    const int t = threadIdx.x;
    if (blockIdx.x >= 313) {
        int idx = (blockIdx.x - 313) * 4 + blockIdx.y;   // 0..403
        int spx;
        if (idx < 102) spx = idx;
        else if (idx < 204) spx = 10302 + (idx - 102);
        else { int k = idx - 204; spx = (1 + (k >> 1)) * 102 + (k & 1) * 101; }
        size_t o = (size_t)spx * 1024 + t * 4;
        *(ushort4*)&xt1[o] = make_ushort4(0, 0, 0, 0);
        *(ushort4*)&xt2[o] = make_ushort4(0, 0, 0, 0);
        return;
    }
    const int px0 = blockIdx.x * 32;
    const int ci0 = blockIdx.y * 256;
    for (int it = 0; it < 32; ++it) {
        int idx = it * 256 + t;
        int a = idx >> 5, b = idx & 31;
        int p = px0 + b;
        float v = (p < NPIX) ? x[(size_t)(ci0 + a) * NPIX + p] : 0.f;
        __half h1 = __float2half_rn(v);
        __half h2 = __float2half_rn(v - __half2float(h1));
        sh[b][a] = ((unsigned)__half_as_ushort(h1) << 16) | __half_as_ushort(h2);
    }
    __syncthreads();
    for (int it = 0; it < 8; ++it) {
        int u = it * 256 + t;
        int pl = u >> 6, cq = u & 63;
        int p = px0 + pl;
        if (p >= NPIX) continue;
        int r = p / 100, c = p - r * 100;
        int spx = (r + 1) * 102 + (c + 1);
        unsigned w0 = sh[pl][cq * 4 + 0], w1 = sh[pl][cq * 4 + 1];
        unsigned w2 = sh[pl][cq * 4 + 2], w3 = sh[pl][cq * 4 + 3];
        ushort4 v1 = make_ushort4((u16)(w0 >> 16), (u16)(w1 >> 16), (u16)(w2 >> 16), (u16)(w3 >> 16));
        ushort4 v2 = make_ushort4((u16)(w0 & 0xffff), (u16)(w1 & 0xffff), (u16)(w2 & 0xffff), (u16)(w3 & 0xffff));
        size_t o = (size_t)spx * 1024 + ci0 + cq * 4;
        *(ushort4*)&xt1[o] = v1;
        *(ushort4*)&xt2[o] = v2;
    }
}

// ---------------------------------------------------------------------------
// wsplit (+fused wh_prep): blocks < COUT split w1 -> wp1/wp2 fp16 [tap][co][ci]
// x1024; blocks >= COUT transpose head weights into wh[ci][48].
// ---------------------------------------------------------------------------
__global__ __launch_bounds__(256) void wsplit(
    const float* __restrict__ w1, u16* __restrict__ wp1, u16* __restrict__ wp2,
    const float* __restrict__ wcls, const float* __restrict__ wbox,
    float* __restrict__ wh)
{
    __shared__ float sw[K9];
    const int t = threadIdx.x;
    if (blockIdx.x >= COUT) {
        int e = (blockIdx.x - COUT) * 256 + t;     // over CIN*KH
        if (e < CIN * KH) {
            int c = e / KH, k = e - c * KH;
            float v = 0.f;
            if (k < 9) v = wcls[k * CIN + c];
            else if (k < 45) v = wbox[(k - 9) * CIN + c];
            wh[e] = v;
        }
        return;
    }
    const int co = blockIdx.x;
    for (int it = 0; it < 36; ++it)
        sw[it * 256 + t] = w1[(size_t)co * K9 + it * 256 + t];
    __syncthreads();
    for (int tap = 0; tap < 9; ++tap) {
        for (int it = 0; it < 4; ++it) {
            int ci = it * 256 + t;
            float v = sw[ci * 9 + tap] * WSCALE;
            __half h1 = __float2half_rn(v);
            __half h2 = __float2half_rn(v - __half2float(h1));
            size_t o = (size_t)tap * (COUT * 1024) + (size_t)co * 1024 + ci;
            wp1[o] = __half_as_ushort(h1);
            wp2[o] = __half_as_ushort(h2);
        }
    }
}

// ---------------------------------------------------------------------------
// conv_mfma (R2 version, best measured): 3x3 conv via fp16-split MFMA.
// Block 128co x 160px, 256 thr, wave tile 64x80. 2-phase global_load_lds
// pipeline, XOR bank swizzle via pre-swizzled global source + swizzled ds_read.
// ---------------------------------------------------------------------------
__global__ __launch_bounds__(256, 2) void conv_mfma(
    const u16* __restrict__ xt1, const u16* __restrict__ xt2,
    const u16* __restrict__ wp1, const u16* __restrict__ wp2,
    const float* __restrict__ b1, float* __restrict__ y)
{
    __shared__ __align__(16) char lds[2 * BUFB];   // per buf: A1@0 A2@8192 B1@16384 B2@26624
    const int t = threadIdx.x;
    const int co0 = blockIdx.x * 128;
    const int px0 = blockIdx.y * PXT;
    const int lane = t & 63;
    const int wv = __builtin_amdgcn_readfirstlane(t >> 6);
    const int wm = (wv >> 1) * 64;          // co sub-tile
    const int wn = (wv & 1) * 80;           // px sub-tile

    const int qs = (lane & 3) ^ ((lane >> 3) & 3);
    const int aln = (lane >> 2) * 1024 + qs * 8;

    const int ar0 = wv * 32, ar1 = wv * 32 + 16;
    const size_t aOff0 = (size_t)(co0 + ar0) * 1024 + aln;
    const size_t aOff1 = (size_t)(co0 + ar1) * 1024 + aln;

    const int nb = (wv < 2) ? 3 : 2;
    size_t bOff[3]; int bLds[3];
#pragma unroll
    for (int s = 0; s < 3; ++s) {
        int r0 = (wv + 4 * s) * 16;
        if (r0 >= PXT) r0 = 0;
        int p = px0 + r0 + (lane >> 2);
        if (p > NPIX - 1) p = NPIX - 1;
        int rr = p / 100, cc = p - rr * 100;
        bOff[s] = (size_t)((rr + 1) * 102 + cc + 1) * 1024 + qs * 8;
        bLds[s] = r0 * 64;
    }

    const int qf = ((lane >> 4) ^ (((lane & 15) >> 1) & 3)) * 16;
    const int fA = (wm + (lane & 15)) * 64 + qf;
    const int fB = 16384 + (wn + (lane & 15)) * 64 + qf;

    f32x4 acc[4][5] = {};

    auto STAGE = [&](int buf, int tap, int ci0) {
        const int dy = (tap * 11) >> 5;
        const int tsh = (dy - 1) * 102 + (tap - dy * 3) - 1;
        const size_t adelta = (size_t)tap * 1048576 + ci0;
        const ptrdiff_t bdelta = (ptrdiff_t)tsh * 1024 + ci0;
        char* lb = lds + buf * BUFB;
        gload16(wp1 + aOff0 + adelta, lb + ar0 * 64);
        gload16(wp1 + aOff1 + adelta, lb + ar1 * 64);
        gload16(wp2 + aOff0 + adelta, lb + ABYTES + ar0 * 64);
        gload16(wp2 + aOff1 + adelta, lb + ABYTES + ar1 * 64);
#pragma unroll
        for (int s = 0; s < 3; ++s) {
            if (s < nb) {
                gload16(xt1 + (ptrdiff_t)bOff[s] + bdelta, lb + 16384 + bLds[s]);
                gload16(xt2 + (ptrdiff_t)bOff[s] + bdelta, lb + 26624 + bLds[s]);
            }
        }
    };

    auto COMPUTE = [&](int buf) {
        const char* lb = lds + buf * BUFB;
        f16x8 A1[4], A2[4], B1[5], B2[5];
#pragma unroll
        for (int mi = 0; mi < 4; ++mi) {
            A1[mi] = *(const f16x8*)(lb + fA + mi * 1024);
            A2[mi] = *(const f16x8*)(lb + ABYTES + fA + mi * 1024);
        }
#pragma unroll
        for (int ni = 0; ni < 5; ++ni) {
            B1[ni] = *(const f16x8*)(lb + fB + ni * 1024);
            B2[ni] = *(const f16x8*)(lb + BBYTES + fB + ni * 1024);
        }
#pragma unroll
        for (int mi = 0; mi < 4; ++mi)
#pragma unroll
            for (int ni = 0; ni < 5; ++ni) {
                acc[mi][ni] = __builtin_amdgcn_mfma_f32_16x16x32_f16(A1[mi], B1[ni], acc[mi][ni], 0, 0, 0);
                acc[mi][ni] = __builtin_amdgcn_mfma_f32_16x16x32_f16(A1[mi], B2[ni], acc[mi][ni], 0, 0, 0);
                acc[mi][ni] = __builtin_amdgcn_mfma_f32_16x16x32_f16(A2[mi], B1[ni], acc[mi][ni], 0, 0, 0);
            }
    };

    STAGE(0, 0, 0);
    __syncthreads();
    for (int kk = 0; kk < NSTEP - 1; ++kk) {
        const int kn = kk + 1;
        STAGE(kn & 1, kn >> 5, (kn & 31) << 5);
        COMPUTE(kk & 1);
        __syncthreads();
    }
    COMPUTE((NSTEP - 1) & 1);

    const int q4 = (lane >> 4) * 4, nl = lane & 15;
    const float inv = 1.0f / WSCALE;
#pragma unroll
    for (int mi = 0; mi < 4; ++mi) {
        const int cob = co0 + wm + mi * 16 + q4;
        const float bb0 = b1[cob + 0], bb1 = b1[cob + 1];
        const float bb2 = b1[cob + 2], bb3 = b1[cob + 3];
#pragma unroll
        for (int ni = 0; ni < 5; ++ni) {
            const int px = px0 + wn + ni * 16 + nl;
            if (px < NPIX) {
                y[(size_t)(cob + 0) * NPIX + px] = fmaxf(acc[mi][ni][0] * inv + bb0, 0.f);
                y[(size_t)(cob + 1) * NPIX + px] = fmaxf(acc[mi][ni][1] * inv + bb1, 0.f);
                y[(size_t)(cob + 2) * NPIX + px] = fmaxf(acc[mi][ni][2] * inv + bb2, 0.f);
                y[(size_t)(cob + 3) * NPIX + px] = fmaxf(acc[mi][ni][3] * inv + bb3, 0.f);
            }
        }
    }
}

// ---------------------------------------------------------------------------
// rpn_head (pixel-major, +fused key padding): blocks >= HEADB zero the sort-key
// pad region [NANCH, SORTN).
// ---------------------------------------------------------------------------
__global__ __launch_bounds__(256) void rpn_head(
    const float* __restrict__ y, const float* __restrict__ wh,
    const float* __restrict__ bcls, const float* __restrict__ bbox,
    const float* __restrict__ am, const int* __restrict__ ishape,
    float* __restrict__ out_scores, float* __restrict__ out_deltas,
    float4* __restrict__ boxes, unsigned long long* __restrict__ keys)
{
    __shared__ float red[4][64][KH + 1];
    const int t = threadIdx.x;
    if (blockIdx.x >= HEADB) {
        int i = NANCH + (blockIdx.x - HEADB) * 256 + t;
        if (i < SORTN) keys[i] = 0ull;
        return;
    }
    const int lane = t & 63;
    const int q = __builtin_amdgcn_readfirstlane(t >> 6);
    const int p = blockIdx.x * 64 + lane;
    const int pp = (p < NPIX) ? p : (NPIX - 1);

    float acc[45];
#pragma unroll
    for (int k = 0; k < 45; ++k) acc[k] = 0.f;

    const float* __restrict__ yq  = y  + (size_t)q * 256 * NPIX + pp;
    const float* __restrict__ whq = wh + (size_t)q * 256 * KH;
    for (int c = 0; c < 256; ++c) {
        float yv = yq[(size_t)c * NPIX];
        const float* wr = whq + c * KH;
#pragma unroll
        for (int k = 0; k < 45; ++k) acc[k] += yv * wr[k];
    }

#pragma unroll
    for (int k = 0; k < 45; ++k) red[q][lane][k] = acc[k];
    __syncthreads();

    if (t >= 64 || p >= NPIX) return;

    float s[45];
#pragma unroll
    for (int k = 0; k < 45; ++k)
        s[k] = (red[0][lane][k] + red[1][lane][k]) + (red[2][lane][k] + red[3][lane][k]);

    const float imh = (float)ishape[1], imw = (float)ishape[2];
#pragma unroll
    for (int a = 0; a < 9; ++a) {
        const int i = p * NA + a;
        float logit = s[a] + bcls[a];
        float score = 1.f / (1.f + expf(-logit));
        float d0 = s[9 + a * 4 + 0] + bbox[a * 4 + 0];
        float d1 = s[9 + a * 4 + 1] + bbox[a * 4 + 1];
        float d2 = s[9 + a * 4 + 2] + bbox[a * 4 + 2];
        float d3 = s[9 + a * 4 + 3] + bbox[a * 4 + 3];
        out_scores[i] = score;
        out_deltas[i * 4 + 0] = d0;
        out_deltas[i * 4 + 1] = d1;
        out_deltas[i * 4 + 2] = d2;
        out_deltas[i * 4 + 3] = d3;

        float cy = am[i * 4 + 0], cx = am[i * 4 + 1];
        float ah = am[i * 4 + 2], aw = am[i * 4 + 3];
        float ctry = cy + d0 * ah, ctrx = cx + d1 * aw;
        float hh = ah * expf(d2), ww = aw * expf(d3);
        float y1 = fmaxf(ctry - 0.5f * hh, 0.f);
        float x1 = fmaxf(ctrx - 0.5f * ww, 0.f);
        float y2 = fminf(ctry + 0.5f * hh, imh);
        float x2 = fminf(ctrx + 0.5f * ww, imw);
        boxes[i] = make_float4(y1, x1, y2, x2);
        unsigned sb = __float_as_uint(score);
        keys[i] = ((unsigned long long)sb << 32) | (unsigned)i;
    }
}

// ---------------------------------------------------------------------------
// Bitonic sort (descending) of SORTN u64 keys — 8192-element blocks (64KB LDS,
// 1024 thr). local8k covers L<=8192; lmerge8k covers d<=4096; gpass for
// d>=8192. Final lmerge8k block 0 holds the top-8192 in LDS and fuses the
// box gather + min-size ballot.
// ---------------------------------------------------------------------------
__global__ __launch_bounds__(1024) void bitonic_local8k(unsigned long long* keys)
{
    __shared__ unsigned long long s[8192];
    const int base = blockIdx.x * 8192, t = threadIdx.x;
    for (int k = t; k < 8192; k += 1024) s[k] = keys[base + k];
    for (int L = 2; L <= 8192; L <<= 1) {
        for (int d = L >> 1; d >= 1; d >>= 1) {
            __syncthreads();
            for (int pr = t; pr < 4096; pr += 1024) {
                int i = ((pr & ~(d - 1)) << 1) | (pr & (d - 1));
                int j = i + d;
                bool desc = (((base + i) & L) == 0);
                unsigned long long va = s[i], vb = s[j];
                bool sw = desc ? (va < vb) : (va > vb);
                if (sw) { s[i] = vb; s[j] = va; }
            }
        }
    }
    __syncthreads();
    for (int k = t; k < 8192; k += 1024) keys[base + k] = s[k];
}

__global__ __launch_bounds__(256) void bitonic_gpass(unsigned long long* keys, int L, int d)
{
    int pr = blockIdx.x * 256 + threadIdx.x;
    int i = ((pr & ~(d - 1)) << 1) | (pr & (d - 1));
    int j = i + d;
    bool desc = ((i & L) == 0);
    unsigned long long va = keys[i], vb = keys[j];
    bool sw = desc ? (va < vb) : (va > vb);
    if (sw) { keys[i] = vb; keys[j] = va; }
}

__global__ __launch_bounds__(1024) void bitonic_lmerge8k(
    unsigned long long* keys, int L,
    const float4* __restrict__ boxes, float4* __restrict__ box_s,
    unsigned long long* __restrict__ validw)
{
    __shared__ unsigned long long s[8192];
    const int base = blockIdx.x * 8192, t = threadIdx.x;
    for (int k = t; k < 8192; k += 1024) s[k] = keys[base + k];
    const bool desc = ((base & L) == 0);
    for (int d = 4096; d >= 1; d >>= 1) {
        __syncthreads();
        for (int pr = t; pr < 4096; pr += 1024) {
            int i = ((pr & ~(d - 1)) << 1) | (pr & (d - 1));
            int j = i + d;
            unsigned long long va = s[i], vb = s[j];
            bool sw = desc ? (va < vb) : (va > vb);
            if (sw) { s[i] = vb; s[j] = va; }
        }
    }
    __syncthreads();
    for (int k = t; k < 8192; k += 1024) keys[base + k] = s[k];
    // final merge, block 0: s[0..8191] is the global top-8192 (descending) —
    // fused gather of the top-PRE boxes + min-size valid ballot.
    if (L == SORTN && blockIdx.x == 0) {
        for (int k = t; k < 6144; k += 1024) {
            bool valid = false;
            if (k < PRE) {
                unsigned idx = (unsigned)(s[k] & 0xffffffffull);
                float4 b = boxes[idx];
                box_s[k] = b;
                valid = ((b.z - b.x) >= 16.f) && ((b.w - b.y) >= 16.f);
            }
            unsigned long long bal = __ballot(valid);
            if ((t & 63) == 0) validw[k >> 6] = bal;
        }
    }
}

// ---------------------------------------------------------------------------
__global__ __launch_bounds__(128) void nms_mask(
    const float4* __restrict__ box_s, unsigned long long* __restrict__ mask)
{
    const int i = blockIdx.x;
    const int w = threadIdx.x;
    if (w >= NW) return;
    float4 bi = box_s[i];
    float areai = (bi.z - bi.x) * (bi.w - bi.y);
    unsigned long long m = 0ull;
    const int j0 = w * 64;
    if (j0 + 63 > i) {
#pragma unroll 4
        for (int b = 0; b < 64; ++b) {
            int j = j0 + b;
            if (j <= i || j >= PRE) continue;
            float4 bj = box_s[j];
            float areaj = (bj.z - bj.x) * (bj.w - bj.y);
            float iy1 = fmaxf(bi.x, bj.x), ix1 = fmaxf(bi.y, bj.y);
            float iy2 = fminf(bi.z, bj.z), ix2 = fminf(bi.w, bj.w);
            float inter = fmaxf(iy2 - iy1, 0.f) * fmaxf(ix2 - ix1, 0.f);
            float iou = inter / (areai + areaj - inter + 1e-8f);
            if (iou > 0.7f) m |= (1ull << b);
        }
    }
    mask[(size_t)i * MASKW + w] = m;
}

// ---------------------------------------------------------------------------
// nms_scan (+fused out_gather): wave 0 runs the serial suppression scan into
// LDS keepw; then all 256 threads do the compacted output write.
// ---------------------------------------------------------------------------
__global__ __launch_bounds__(256) void nms_scan_out(
    const unsigned long long* __restrict__ mask,
    const unsigned long long* __restrict__ validw,
    const float4* __restrict__ box_s, float* __restrict__ outp)
{
    __shared__ unsigned long long kw_s[NW];
    __shared__ int prefix[NW];
    const int t = threadIdx.x;
    if (t < 64) {
        const int l = t;
        unsigned long long r0 = ~validw[l];
        unsigned long long r1 = (l < NW - 64) ? ~validw[64 + l] : ~0ull;
        unsigned long long p0[16], p1[16];
#pragma unroll
        for (int k = 0; k < 16; ++k) {
            p0[k] = mask[(size_t)k * MASKW + l];
            p1[k] = (l < NW - 64) ? mask[(size_t)k * MASKW + 64 + l] : 0ull;
        }
        int kept = 0;
        for (int w = 0; w < NW && kept < POST; ++w) {
            unsigned long long Wc = (w < 64) ? __shfl(r0, w) : __shfl(r1, w - 64);
#pragma unroll 16
            for (int b = 0; b < 64; ++b) {
                int i = w * 64 + b;
                if (i >= PRE) break;
                int slot = i & 15;
                unsigned long long m0 = p0[slot], m1 = p1[slot];
                int nxt = i + 16;
                if (nxt < PRE) {
                    p0[slot] = mask[(size_t)nxt * MASKW + l];
                    p1[slot] = (l < NW - 64) ? mask[(size_t)nxt * MASKW + 64 + l] : 0ull;
                }
                if (!((Wc >> b) & 1ull)) {
                    r0 |= m0; r1 |= m1;
                    Wc = (w < 64) ? __shfl(r0, w) : __shfl(r1, w - 64);
                    ++kept;
                }
            }
        }
        kw_s[l] = ~r0;
        if (l < NW - 64) kw_s[64 + l] = ~r1;
    }
    __syncthreads();
    if (t == 0) {
        int cum = 0;
        for (int w = 0; w < NW; ++w) { prefix[w] = cum; cum += __popcll(kw_s[w]); }
    }
    for (int k = t; k < POST * 4; k += 256) outp[k] = 0.f;
    __syncthreads();
    for (int i = t; i < PRE; i += 256) {
        int w = i >> 6, b = i & 63;
        unsigned long long kw = kw_s[w];
        if ((kw >> b) & 1ull) {
            int rank = prefix[w] + __popcll(kw & ((1ull << b) - 1ull));
            if (rank < POST) {
                float4 bx = box_s[i];
                outp[rank * 4 + 0] = bx.x;
                outp[rank * 4 + 1] = bx.y;
                outp[rank * 4 + 2] = bx.z;
                outp[rank * 4 + 3] = bx.w;
            }
        }
    }
}

// ---------------------------------------------------------------------------
extern "C" void kernel_launch(void* const* d_in, const int* in_sizes, int n_in,
                              void* d_out, int out_size, void* d_ws, size_t ws_size,
                              hipStream_t stream)
{
    const float* x      = (const float*)d_in[0];
    const int*   ishape = (const int*)  d_in[1];
    const float* am     = (const float*)d_in[2];
    const float* w1   = (const float*)d_in[6];
    const float* b1   = (const float*)d_in[7];
    const float* wcls = (const float*)d_in[8];
    const float* bcls = (const float*)d_in[9];
    const float* wbox = (const float*)d_in[10];
    const float* bbox = (const float*)d_in[11];
    float* out = (float*)d_out;

    char* ws = (char*)d_ws;
    size_t off = 0;
    float* y  = (float*)(ws + off);  off += (size_t)COUT * NPIX * 4;
    u16* xt1  = (u16*)(ws + off);    off += (size_t)SPAD * 1024 * 2;
    u16* xt2  = (u16*)(ws + off);    off += (size_t)SPAD * 1024 * 2;
    u16* wp1  = (u16*)(ws + off);    off += (size_t)9 * COUT * 1024 * 2;
    u16* wp2  = (u16*)(ws + off);    off += (size_t)9 * COUT * 1024 * 2;
    float4* boxes = (float4*)(ws + off);              off += (size_t)NANCH * 16;
    unsigned long long* keys = (unsigned long long*)(ws + off); off += (size_t)SORTN * 8;
    float4* box_s = (float4*)(ws + off);              off += (size_t)PRE * 16;
    unsigned long long* validw = (unsigned long long*)(ws + off); off += 96 * 8;
    unsigned long long* maskb  = (unsigned long long*)(ws + off); off += (size_t)PRE * MASKW * 8;
    float* wh = (float*)(ws + off);  off += (size_t)CIN * KH * 4;

    xsplit<<<dim3(414, 4), 256, 0, stream>>>(x, xt1, xt2);
    wsplit<<<COUT + (CIN * KH + 255) / 256, 256, 0, stream>>>(w1, wp1, wp2, wcls, wbox, wh);
    conv_mfma<<<dim3(8, (NPIX + PXT - 1) / PXT), 256, 0, stream>>>(xt1, xt2, wp1, wp2, b1, y);
    rpn_head<<<HEADB + (SORTN - NANCH + 255) / 256, 256, 0, stream>>>(
        y, wh, bcls, bbox, am, ishape, out, out + NANCH, boxes, keys);
    bitonic_local8k<<<SORTN / 8192, 1024, 0, stream>>>(keys);
    for (int L = 16384; L <= SORTN; L <<= 1) {
        for (int d = L >> 1; d >= 8192; d >>= 1)
            bitonic_gpass<<<SORTN / 512, 256, 0, stream>>>(keys, L, d);
        bitonic_lmerge8k<<<SORTN / 8192, 1024, 0, stream>>>(keys, L, boxes, box_s, validw);
    }
    nms_mask<<<PRE, 128, 0, stream>>>(box_s, maskb);
    nms_scan_out<<<1, 256, 0, stream>>>(maskb, validw, box_s, out + (size_t)NANCH * 5);
}

// Round 8
// 1076.231 us; speedup vs baseline: 1.1740x; 1.0665x over previous
//
#include <hip/hip_runtime.h>
#include <hip/hip_fp16.h>
#include <stdint.h>

#define HH 100
#define WW 100
#define NPIX 10000
#define CIN 1024
#define COUT 1024
#define NA 9
#define NANCH 90000
#define PRE 6000
#define POST 300
#define SORTN 131072
#define MASKW 96
#define NW 94
#define K9 9216          // CIN*9
#define SPAD 10404       // 102*102 padded pixel rows
#define WSCALE 1024.0f   // exact pow2 pre-scale for w split (avoids fp16 subnormals)
#define KH 48            // padded head output count (9 cls + 36 box + 3 pad)

// conv tiling: 256co x 160px, 512 thr (8 waves, 2/SIMD), 3 LDS buffers,
// counted-vmcnt 2-step-lookahead pipeline (T3/T4).
#define PXT 160
#define BUFB 53248       // A1@0(16K) A2@16384(16K) B1@32768(10K) B2@43008(10K)
#define NSTEP 288        // 9 taps x 32 ci-steps

#define HEADB 157        // rpn_head real blocks = (NPIX+63)/64

typedef unsigned short u16;
typedef _Float16 f16x8 __attribute__((ext_vector_type(8)));
typedef float f32x4 __attribute__((ext_vector_type(4)));

__device__ __forceinline__ void gload16(const u16* g, char* l)
{
    __builtin_amdgcn_global_load_lds((const void*)g, (void*)l, 16, 0, 0);
}

// ---------------------------------------------------------------------------
// xsplit (+fused border zeroing)
// ---------------------------------------------------------------------------
__global__ __launch_bounds__(256) void xsplit(
    const float* __restrict__ x, u16* __restrict__ xt1, u16* __restrict__ xt2)
{
    __shared__ unsigned sh[32][257];   // [px_local][ci_local]: h1<<16 | h2
    const int t = threadIdx.x;
    if (blockIdx.x >= 313) {
        int idx = (blockIdx.x - 313) * 4 + blockIdx.y;   // 0..403
        int spx;
        if (idx < 102) spx = idx;
        else if (idx < 204) spx = 10302 + (idx - 102);
        else { int k = idx - 204; spx = (1 + (k >> 1)) * 102 + (k & 1) * 101; }
        size_t o = (size_t)spx * 1024 + t * 4;
        *(ushort4*)&xt1[o] = make_ushort4(0, 0, 0, 0);
        *(ushort4*)&xt2[o] = make_ushort4(0, 0, 0, 0);
        return;
    }
    const int px0 = blockIdx.x * 32;
    const int ci0 = blockIdx.y * 256;
    for (int it = 0; it < 32; ++it) {
        int idx = it * 256 + t;
        int a = idx >> 5, b = idx & 31;
        int p = px0 + b;
        float v = (p < NPIX) ? x[(size_t)(ci0 + a) * NPIX + p] : 0.f;
        __half h1 = __float2half_rn(v);
        __half h2 = __float2half_rn(v - __half2float(h1));
        sh[b][a] = ((unsigned)__half_as_ushort(h1) << 16) | __half_as_ushort(h2);
    }
    __syncthreads();
    for (int it = 0; it < 8; ++it) {
        int u = it * 256 + t;
        int pl = u >> 6, cq = u & 63;
        int p = px0 + pl;
        if (p >= NPIX) continue;
        int r = p / 100, c = p - r * 100;
        int spx = (r + 1) * 102 + (c + 1);
        unsigned w0 = sh[pl][cq * 4 + 0], w1 = sh[pl][cq * 4 + 1];
        unsigned w2 = sh[pl][cq * 4 + 2], w3 = sh[pl][cq * 4 + 3];
        ushort4 v1 = make_ushort4((u16)(w0 >> 16), (u16)(w1 >> 16), (u16)(w2 >> 16), (u16)(w3 >> 16));
        ushort4 v2 = make_ushort4((u16)(w0 & 0xffff), (u16)(w1 & 0xffff), (u16)(w2 & 0xffff), (u16)(w3 & 0xffff));
        size_t o = (size_t)spx * 1024 + ci0 + cq * 4;
        *(ushort4*)&xt1[o] = v1;
        *(ushort4*)&xt2[o] = v2;
    }
}

// ---------------------------------------------------------------------------
// wsplit (+fused wh_prep)
// ---------------------------------------------------------------------------
__global__ __launch_bounds__(256) void wsplit(
    const float* __restrict__ w1, u16* __restrict__ wp1, u16* __restrict__ wp2,
    const float* __restrict__ wcls, const float* __restrict__ wbox,
    float* __restrict__ wh)
{
    __shared__ float sw[K9];
    const int t = threadIdx.x;
    if (blockIdx.x >= COUT) {
        int e = (blockIdx.x - COUT) * 256 + t;     // over CIN*KH
        if (e < CIN * KH) {
            int c = e / KH, k = e - c * KH;
            float v = 0.f;
            if (k < 9) v = wcls[k * CIN + c];
            else if (k < 45) v = wbox[(k - 9) * CIN + c];
            wh[e] = v;
        }
        return;
    }
    const int co = blockIdx.x;
    for (int it = 0; it < 36; ++it)
        sw[it * 256 + t] = w1[(size_t)co * K9 + it * 256 + t];
    __syncthreads();
    for (int tap = 0; tap < 9; ++tap) {
        for (int it = 0; it < 4; ++it) {
            int ci = it * 256 + t;
            float v = sw[ci * 9 + tap] * WSCALE;
            __half h1 = __float2half_rn(v);
            __half h2 = __float2half_rn(v - __half2float(h1));
            size_t o = (size_t)tap * (COUT * 1024) + (size_t)co * 1024 + ci;
            wp1[o] = __half_as_ushort(h1);
            wp2[o] = __half_as_ushort(h2);
        }
    }
}

// ---------------------------------------------------------------------------
// conv_mfma: 3x3 conv via fp16-split MFMA. Block 256co x 160px, 512 thr,
// wave tile 64x80 (m4 x n5), 8 waves (4co x 2px). K = 9 taps x 1024 ci,
// kstep 32. 3-buffer LDS, 2-step lookahead, counted s_waitcnt vmcnt(6)
// (never 0 in steady state) + raw s_barrier. Buffer pointers computed
// arithmetically from an int index (pointer-array init of LDS doesn't
// compile on gfx950: addrspacecast in static initializer).
// ---------------------------------------------------------------------------
__global__ __launch_bounds__(512, 1) void conv_mfma(
    const u16* __restrict__ xt1, const u16* __restrict__ xt2,
    const u16* __restrict__ wp1, const u16* __restrict__ wp2,
    const float* __restrict__ b1, float* __restrict__ y)
{
    __shared__ __align__(16) char lds[3 * BUFB];   // 156 KiB
    const int t = threadIdx.x;
    const int co0 = blockIdx.x * 256;
    const int px0 = blockIdx.y * PXT;
    const int lane = t & 63;
    const int wv = __builtin_amdgcn_readfirstlane(t >> 6);   // 0..7
    const int wm = (wv >> 1) * 64;          // co sub-tile: 0,64,128,192
    const int wn = (wv & 1) * 80;           // px sub-tile: 0,80

    // staging: within a 16-row issue unit, lane -> row r0+(lane>>2), dest
    // chunk lane&3; source chunk swizzled qs (involution valid: r0 % 16 == 0)
    const int qs = (lane & 3) ^ ((lane >> 3) & 3);

    // A: wave wv stages co rows [wv*32, wv*32+32) for both planes (4 issues)
    const int ar0 = wv * 32, ar1 = wv * 32 + 16;
    const size_t aOff0 = (size_t)(co0 + ar0 + (lane >> 2)) * 1024 + qs * 8;
    const size_t aOff1 = (size_t)(co0 + ar1 + (lane >> 2)) * 1024 + qs * 8;

    // B: unit u covers rows [u*16,u*16+16); wave wv takes u=wv and (wv<2) 8+wv
    const int nbu = (wv < 2) ? 2 : 1;
    size_t bOff[2]; int bLds[2];
#pragma unroll
    for (int s = 0; s < 2; ++s) {
        int r0 = (wv + 8 * s) * 16;
        if (r0 >= PXT) r0 = 0;                    // unused slot
        int p = px0 + r0 + (lane >> 2);
        if (p > NPIX - 1) p = NPIX - 1;
        int rr = p / 100, cc = p - rr * 100;
        bOff[s] = (size_t)((rr + 1) * 102 + cc + 1) * 1024 + qs * 8;
        bLds[s] = r0 * 64;
    }

    // fragment reads: row = base + (lane&15), chunk lane>>4, swizzled qf
    const int qf = ((lane >> 4) ^ (((lane & 15) >> 1) & 3)) * 16;
    const int fA = (wm + (lane & 15)) * 64 + qf;
    const int fB = 32768 + (wn + (lane & 15)) * 64 + qf;

    f32x4 acc[4][5] = {};

    auto STAGE = [&](int buf, int step) {
        char* lb = lds + buf * BUFB;
        const int tap = step >> 5;
        const int ci0 = (step & 31) << 5;
        const int dy = (tap * 11) >> 5;            // tap/3 for 0..8
        const int tsh = (dy - 1) * 102 + (tap - dy * 3) - 1;
        const size_t adelta = (size_t)tap * 1048576 + ci0;
        const ptrdiff_t bdelta = (ptrdiff_t)tsh * 1024 + ci0;
        gload16(wp1 + aOff0 + adelta, lb + ar0 * 64);
        gload16(wp1 + aOff1 + adelta, lb + ar1 * 64);
        gload16(wp2 + aOff0 + adelta, lb + 16384 + ar0 * 64);
        gload16(wp2 + aOff1 + adelta, lb + 16384 + ar1 * 64);
#pragma unroll
        for (int s = 0; s < 2; ++s) {
            if (s < nbu) {
                gload16(xt1 + (ptrdiff_t)bOff[s] + bdelta, lb + 32768 + bLds[s]);
                gload16(xt2 + (ptrdiff_t)bOff[s] + bdelta, lb + 43008 + bLds[s]);
            }
        }
    };

    auto COMPUTE = [&](int buf) {
        const char* lb = lds + buf * BUFB;
        f16x8 A1[4], A2[4], B1[5], B2[5];
#pragma unroll
        for (int mi = 0; mi < 4; ++mi) {
            A1[mi] = *(const f16x8*)(lb + fA + mi * 1024);
            A2[mi] = *(const f16x8*)(lb + 16384 + fA + mi * 1024);
        }
#pragma unroll
        for (int ni = 0; ni < 5; ++ni) {
            B1[ni] = *(const f16x8*)(lb + fB + ni * 1024);
            B2[ni] = *(const f16x8*)(lb + fB + 10240 + ni * 1024);
        }
#pragma unroll
        for (int mi = 0; mi < 4; ++mi)
#pragma unroll
            for (int ni = 0; ni < 5; ++ni) {
                acc[mi][ni] = __builtin_amdgcn_mfma_f32_16x16x32_f16(A1[mi], B1[ni], acc[mi][ni], 0, 0, 0);
                acc[mi][ni] = __builtin_amdgcn_mfma_f32_16x16x32_f16(A1[mi], B2[ni], acc[mi][ni], 0, 0, 0);
                acc[mi][ni] = __builtin_amdgcn_mfma_f32_16x16x32_f16(A2[mi], B1[ni], acc[mi][ni], 0, 0, 0);
            }
    };

    // prologue: 2 stages in flight; vmcnt(6) <= min per-stage issues (6), so
    // stage0's loads are fully retired before the barrier.
    STAGE(0, 0);
    STAGE(1, 1);
    asm volatile("s_waitcnt vmcnt(6)" ::: "memory");
    __builtin_amdgcn_s_barrier();

    int cb = 0;
    for (int k = 0; k < NSTEP; ++k) {
        int sb = cb + 2; if (sb >= 3) sb -= 3;
        if (k + 2 < NSTEP) STAGE(sb, k + 2);   // issue 2 steps ahead
        COMPUTE(cb);                            // loads fly under MFMA
        if (k >= NSTEP - 2) {
            asm volatile("s_waitcnt vmcnt(0)" ::: "memory");   // epilogue drain
        } else {
            asm volatile("s_waitcnt vmcnt(6)" ::: "memory");   // counted wait
        }
        __builtin_amdgcn_s_barrier();
        if (++cb == 3) cb = 0;
    }

    // epilogue: D row=(lane>>4)*4+reg (co), col=lane&15 (px); descale+bias+relu
    const int q4 = (lane >> 4) * 4, nl = lane & 15;
    const float inv = 1.0f / WSCALE;
#pragma unroll
    for (int mi = 0; mi < 4; ++mi) {
        const int cob = co0 + wm + mi * 16 + q4;
        const float bb0 = b1[cob + 0], bb1 = b1[cob + 1];
        const float bb2 = b1[cob + 2], bb3 = b1[cob + 3];
#pragma unroll
        for (int ni = 0; ni < 5; ++ni) {
            const int px = px0 + wn + ni * 16 + nl;
            if (px < NPIX) {
                y[(size_t)(cob + 0) * NPIX + px] = fmaxf(acc[mi][ni][0] * inv + bb0, 0.f);
                y[(size_t)(cob + 1) * NPIX + px] = fmaxf(acc[mi][ni][1] * inv + bb1, 0.f);
                y[(size_t)(cob + 2) * NPIX + px] = fmaxf(acc[mi][ni][2] * inv + bb2, 0.f);
                y[(size_t)(cob + 3) * NPIX + px] = fmaxf(acc[mi][ni][3] * inv + bb3, 0.f);
            }
        }
    }
}

// ---------------------------------------------------------------------------
// rpn_head (pixel-major, +fused key padding)
// ---------------------------------------------------------------------------
__global__ __launch_bounds__(256) void rpn_head(
    const float* __restrict__ y, const float* __restrict__ wh,
    const float* __restrict__ bcls, const float* __restrict__ bbox,
    const float* __restrict__ am, const int* __restrict__ ishape,
    float* __restrict__ out_scores, float* __restrict__ out_deltas,
    float4* __restrict__ boxes, unsigned long long* __restrict__ keys)
{
    __shared__ float red[4][64][KH + 1];
    const int t = threadIdx.x;
    if (blockIdx.x >= HEADB) {
        int i = NANCH + (blockIdx.x - HEADB) * 256 + t;
        if (i < SORTN) keys[i] = 0ull;
        return;
    }
    const int lane = t & 63;
    const int q = __builtin_amdgcn_readfirstlane(t >> 6);
    const int p = blockIdx.x * 64 + lane;
    const int pp = (p < NPIX) ? p : (NPIX - 1);

    float acc[45];
#pragma unroll
    for (int k = 0; k < 45; ++k) acc[k] = 0.f;

    const float* __restrict__ yq  = y  + (size_t)q * 256 * NPIX + pp;
    const float* __restrict__ whq = wh + (size_t)q * 256 * KH;
    for (int c = 0; c < 256; ++c) {
        float yv = yq[(size_t)c * NPIX];
        const float* wr = whq + c * KH;
#pragma unroll
        for (int k = 0; k < 45; ++k) acc[k] += yv * wr[k];
    }

#pragma unroll
    for (int k = 0; k < 45; ++k) red[q][lane][k] = acc[k];
    __syncthreads();

    if (t >= 64 || p >= NPIX) return;

    float s[45];
#pragma unroll
    for (int k = 0; k < 45; ++k)
        s[k] = (red[0][lane][k] + red[1][lane][k]) + (red[2][lane][k] + red[3][lane][k]);

    const float imh = (float)ishape[1], imw = (float)ishape[2];
#pragma unroll
    for (int a = 0; a < 9; ++a) {
        const int i = p * NA + a;
        float logit = s[a] + bcls[a];
        float score = 1.f / (1.f + expf(-logit));
        float d0 = s[9 + a * 4 + 0] + bbox[a * 4 + 0];
        float d1 = s[9 + a * 4 + 1] + bbox[a * 4 + 1];
        float d2 = s[9 + a * 4 + 2] + bbox[a * 4 + 2];
        float d3 = s[9 + a * 4 + 3] + bbox[a * 4 + 3];
        out_scores[i] = score;
        out_deltas[i * 4 + 0] = d0;
        out_deltas[i * 4 + 1] = d1;
        out_deltas[i * 4 + 2] = d2;
        out_deltas[i * 4 + 3] = d3;

        float cy = am[i * 4 + 0], cx = am[i * 4 + 1];
        float ah = am[i * 4 + 2], aw = am[i * 4 + 3];
        float ctry = cy + d0 * ah, ctrx = cx + d1 * aw;
        float hh = ah * expf(d2), ww = aw * expf(d3);
        float y1 = fmaxf(ctry - 0.5f * hh, 0.f);
        float x1 = fmaxf(ctrx - 0.5f * ww, 0.f);
        float y2 = fminf(ctry + 0.5f * hh, imh);
        float x2 = fminf(ctrx + 0.5f * ww, imw);
        boxes[i] = make_float4(y1, x1, y2, x2);
        unsigned sb = __float_as_uint(score);
        keys[i] = ((unsigned long long)sb << 32) | (unsigned)i;
    }
}

// ---------------------------------------------------------------------------
// Bitonic sort (descending) of SORTN u64 keys — 8192-element blocks.
// ---------------------------------------------------------------------------
__global__ __launch_bounds__(1024) void bitonic_local8k(unsigned long long* keys)
{
    __shared__ unsigned long long s[8192];
    const int base = blockIdx.x * 8192, t = threadIdx.x;
    for (int k = t; k < 8192; k += 1024) s[k] = keys[base + k];
    for (int L = 2; L <= 8192; L <<= 1) {
        for (int d = L >> 1; d >= 1; d >>= 1) {
            __syncthreads();
            for (int pr = t; pr < 4096; pr += 1024) {
                int i = ((pr & ~(d - 1)) << 1) | (pr & (d - 1));
                int j = i + d;
                bool desc = (((base + i) & L) == 0);
                unsigned long long va = s[i], vb = s[j];
                bool sw = desc ? (va < vb) : (va > vb);
                if (sw) { s[i] = vb; s[j] = va; }
            }
        }
    }
    __syncthreads();
    for (int k = t; k < 8192; k += 1024) keys[base + k] = s[k];
}

__global__ __launch_bounds__(256) void bitonic_gpass(unsigned long long* keys, int L, int d)
{
    int pr = blockIdx.x * 256 + threadIdx.x;
    int i = ((pr & ~(d - 1)) << 1) | (pr & (d - 1));
    int j = i + d;
    bool desc = ((i & L) == 0);
    unsigned long long va = keys[i], vb = keys[j];
    bool sw = desc ? (va < vb) : (va > vb);
    if (sw) { keys[i] = vb; keys[j] = va; }
}

__global__ __launch_bounds__(1024) void bitonic_lmerge8k(
    unsigned long long* keys, int L,
    const float4* __restrict__ boxes, float4* __restrict__ box_s,
    unsigned long long* __restrict__ validw)
{
    __shared__ unsigned long long s[8192];
    const int base = blockIdx.x * 8192, t = threadIdx.x;
    for (int k = t; k < 8192; k += 1024) s[k] = keys[base + k];
    const bool desc = ((base & L) == 0);
    for (int d = 4096; d >= 1; d >>= 1) {
        __syncthreads();
        for (int pr = t; pr < 4096; pr += 1024) {
            int i = ((pr & ~(d - 1)) << 1) | (pr & (d - 1));
            int j = i + d;
            unsigned long long va = s[i], vb = s[j];
            bool sw = desc ? (va < vb) : (va > vb);
            if (sw) { s[i] = vb; s[j] = va; }
        }
    }
    __syncthreads();
    for (int k = t; k < 8192; k += 1024) keys[base + k] = s[k];
    // final merge, block 0: s[0..8191] is the global top-8192 (descending) —
    // fused gather of the top-PRE boxes + min-size valid ballot.
    if (L == SORTN && blockIdx.x == 0) {
        for (int k = t; k < 6144; k += 1024) {
            bool valid = false;
            if (k < PRE) {
                unsigned idx = (unsigned)(s[k] & 0xffffffffull);
                float4 b = boxes[idx];
                box_s[k] = b;
                valid = ((b.z - b.x) >= 16.f) && ((b.w - b.y) >= 16.f);
            }
            unsigned long long bal = __ballot(valid);
            if ((t & 63) == 0) validw[k >> 6] = bal;
        }
    }
}

// ---------------------------------------------------------------------------
__global__ __launch_bounds__(128) void nms_mask(
    const float4* __restrict__ box_s, unsigned long long* __restrict__ mask)
{
    const int i = blockIdx.x;
    const int w = threadIdx.x;
    if (w >= NW) return;
    float4 bi = box_s[i];
    float areai = (bi.z - bi.x) * (bi.w - bi.y);
    unsigned long long m = 0ull;
    const int j0 = w * 64;
    if (j0 + 63 > i) {
#pragma unroll 4
        for (int b = 0; b < 64; ++b) {
            int j = j0 + b;
            if (j <= i || j >= PRE) continue;
            float4 bj = box_s[j];
            float areaj = (bj.z - bj.x) * (bj.w - bj.y);
            float iy1 = fmaxf(bi.x, bj.x), ix1 = fmaxf(bi.y, bj.y);
            float iy2 = fminf(bi.z, bj.z), ix2 = fminf(bi.w, bj.w);
            float inter = fmaxf(iy2 - iy1, 0.f) * fmaxf(ix2 - ix1, 0.f);
            float iou = inter / (areai + areaj - inter + 1e-8f);
            if (iou > 0.7f) m |= (1ull << b);
        }
    }
    mask[(size_t)i * MASKW + w] = m;
}

// ---------------------------------------------------------------------------
// nms_scan (+fused out_gather)
// ---------------------------------------------------------------------------
__global__ __launch_bounds__(256) void nms_scan_out(
    const unsigned long long* __restrict__ mask,
    const unsigned long long* __restrict__ validw,
    const float4* __restrict__ box_s, float* __restrict__ outp)
{
    __shared__ unsigned long long kw_s[NW];
    __shared__ int prefix[NW];
    const int t = threadIdx.x;
    if (t < 64) {
        const int l = t;
        unsigned long long r0 = ~validw[l];
        unsigned long long r1 = (l < NW - 64) ? ~validw[64 + l] : ~0ull;
        unsigned long long p0[16], p1[16];
#pragma unroll
        for (int k = 0; k < 16; ++k) {
            p0[k] = mask[(size_t)k * MASKW + l];
            p1[k] = (l < NW - 64) ? mask[(size_t)k * MASKW + 64 + l] : 0ull;
        }
        int kept = 0;
        for (int w = 0; w < NW && kept < POST; ++w) {
            unsigned long long Wc = (w < 64) ? __shfl(r0, w) : __shfl(r1, w - 64);
#pragma unroll 16
            for (int b = 0; b < 64; ++b) {
                int i = w * 64 + b;
                if (i >= PRE) break;
                int slot = i & 15;
                unsigned long long m0 = p0[slot], m1 = p1[slot];
                int nxt = i + 16;
                if (nxt < PRE) {
                    p0[slot] = mask[(size_t)nxt * MASKW + l];
                    p1[slot] = (l < NW - 64) ? mask[(size_t)nxt * MASKW + 64 + l] : 0ull;
                }
                if (!((Wc >> b) & 1ull)) {
                    r0 |= m0; r1 |= m1;
                    Wc = (w < 64) ? __shfl(r0, w) : __shfl(r1, w - 64);
                    ++kept;
                }
            }
        }
        kw_s[l] = ~r0;
        if (l < NW - 64) kw_s[64 + l] = ~r1;
    }
    __syncthreads();
    if (t == 0) {
        int cum = 0;
        for (int w = 0; w < NW; ++w) { prefix[w] = cum; cum += __popcll(kw_s[w]); }
    }
    for (int k = t; k < POST * 4; k += 256) outp[k] = 0.f;
    __syncthreads();
    for (int i = t; i < PRE; i += 256) {
        int w = i >> 6, b = i & 63;
        unsigned long long kw = kw_s[w];
        if ((kw >> b) & 1ull) {
            int rank = prefix[w] + __popcll(kw & ((1ull << b) - 1ull));
            if (rank < POST) {
                float4 bx = box_s[i];
                outp[rank * 4 + 0] = bx.x;
                outp[rank * 4 + 1] = bx.y;
                outp[rank * 4 + 2] = bx.z;
                outp[rank * 4 + 3] = bx.w;
            }
        }
    }
}

// ---------------------------------------------------------------------------
extern "C" void kernel_launch(void* const* d_in, const int* in_sizes, int n_in,
                              void* d_out, int out_size, void* d_ws, size_t ws_size,
                              hipStream_t stream)
{
    const float* x      = (const float*)d_in[0];
    const int*   ishape = (const int*)  d_in[1];
    const float* am     = (const float*)d_in[2];
    const float* w1   = (const float*)d_in[6];
    const float* b1   = (const float*)d_in[7];
    const float* wcls = (const float*)d_in[8];
    const float* bcls = (const float*)d_in[9];
    const float* wbox = (const float*)d_in[10];
    const float* bbox = (const float*)d_in[11];
    float* out = (float*)d_out;

    char* ws = (char*)d_ws;
    size_t off = 0;
    float* y  = (float*)(ws + off);  off += (size_t)COUT * NPIX * 4;
    u16* xt1  = (u16*)(ws + off);    off += (size_t)SPAD * 1024 * 2;
    u16* xt2  = (u16*)(ws + off);    off += (size_t)SPAD * 1024 * 2;
    u16* wp1  = (u16*)(ws + off);    off += (size_t)9 * COUT * 1024 * 2;
    u16* wp2  = (u16*)(ws + off);    off += (size_t)9 * COUT * 1024 * 2;
    float4* boxes = (float4*)(ws + off);              off += (size_t)NANCH * 16;
    unsigned long long* keys = (unsigned long long*)(ws + off); off += (size_t)SORTN * 8;
    float4* box_s = (float4*)(ws + off);              off += (size_t)PRE * 16;
    unsigned long long* validw = (unsigned long long*)(ws + off); off += 96 * 8;
    unsigned long long* maskb  = (unsigned long long*)(ws + off); off += (size_t)PRE * MASKW * 8;
    float* wh = (float*)(ws + off);  off += (size_t)CIN * KH * 4;

    xsplit<<<dim3(414, 4), 256, 0, stream>>>(x, xt1, xt2);
    wsplit<<<COUT + (CIN * KH + 255) / 256, 256, 0, stream>>>(w1, wp1, wp2, wcls, wbox, wh);
    conv_mfma<<<dim3(4, (NPIX + PXT - 1) / PXT), 512, 0, stream>>>(xt1, xt2, wp1, wp2, b1, y);
    rpn_head<<<HEADB + (SORTN - NANCH + 255) / 256, 256, 0, stream>>>(
        y, wh, bcls, bbox, am, ishape, out, out + NANCH, boxes, keys);
    bitonic_local8k<<<SORTN / 8192, 1024, 0, stream>>>(keys);
    for (int L = 16384; L <= SORTN; L <<= 1) {
        for (int d = L >> 1; d >= 8192; d >>= 1)
            bitonic_gpass<<<SORTN / 512, 256, 0, stream>>>(keys, L, d);
        bitonic_lmerge8k<<<SORTN / 8192, 1024, 0, stream>>>(keys, L, boxes, box_s, validw);
    }
    nms_mask<<<PRE, 128, 0, stream>>>(box_s, maskb);
    nms_scan_out<<<1, 256, 0, stream>>>(maskb, validw, box_s, out + (size_t)NANCH * 5);
}